// Round 3
// baseline (262.841 us; speedup 1.0000x reference)
//
#include <hip/hip_runtime.h>
#include <stdint.h>

// MultiHeadAttention: B=4, T=2048, C=1024, H=16, D=64, causal, scale=1/8.
// R11: gemm_qkv -> 256x256 tile, 8 waves, BK=32, FOUR LDS slots (128 KB),
// counted vmcnt(12) (3 K-tiles in flight, never drained in-loop), raw
// s_barrier pairs, fixed 2-way swizzle s(row)=(row^(row>>2))&3, setprio.
// Epilogue: corner-turn in two 128-row passes reusing the 128 KB LDS.
// flash_attn (R10 rho-relabeled in-register softmax) and gemm_out unchanged.
//
// MFMA 16x16x32 bf16 layouts:
//   A frag: m = lane&15, k = (lane>>4)*8 + j
//   B frag: n = lane&15, k = (lane>>4)*8 + j
//   C/D:    col = lane&15, row = (lane>>4)*4 + reg

typedef __attribute__((ext_vector_type(8))) short bf16x8;
typedef __attribute__((ext_vector_type(4))) float f32x4;

#define EXP2F(x) __builtin_amdgcn_exp2f(x)
#define SL2E 0.18033688011112042f  /* 0.125 * log2(e) */
#define FIXED_M 15.0f

template <bool B> struct BoolC { static constexpr bool value = B; };

__device__ __forceinline__ short f2bf(float f) {
  union { float f; unsigned u; } c; c.f = f;
  unsigned u = c.u;
  unsigned r = (u + 0x7fffu + ((u >> 16) & 1u)) >> 16;
  return (short)(unsigned short)r;
}

// sc[j][r] = S at LDS K position 16j + 4kq + r, q = mrow (log2 units).
// Direct in-lane pack -> PV A-fragments (rho relabeling, see flash_attn).
__device__ __forceinline__ void softmax_pack(const f32x4* sc, bf16x8& pa0, bf16x8& pa1) {
  union U { int i[4]; bf16x8 v; };
  U u0, u1;
#pragma unroll
  for (int j = 0; j < 4; ++j) {
    float p0 = EXP2F(sc[j][0]);
    float p1 = EXP2F(sc[j][1]);
    float p2 = EXP2F(sc[j][2]);
    float p3 = EXP2F(sc[j][3]);
    int w0, w1;
    asm("v_cvt_pk_bf16_f32 %0, %1, %2" : "=v"(w0) : "v"(p0), "v"(p1));
    asm("v_cvt_pk_bf16_f32 %0, %1, %2" : "=v"(w1) : "v"(p2), "v"(p3));
    if (j < 2) { u0.i[j * 2] = w0; u0.i[j * 2 + 1] = w1; }
    else       { u1.i[(j - 2) * 2] = w0; u1.i[(j - 2) * 2 + 1] = w1; }
  }
  pa0 = u0.v;
  pa1 = u1.v;
}

// async 16B global -> LDS (dest = wave-uniform base + lane*16)
__device__ __forceinline__ void llds16(const short* g, short* l) {
  __builtin_amdgcn_global_load_lds(
      (const __attribute__((address_space(1))) unsigned int*)g,
      (__attribute__((address_space(3))) unsigned int*)l, 16, 0, 0);
}

__global__ __launch_bounds__(256) void cast_f32_to_bf16(
    const float* __restrict__ src, short* __restrict__ dst, int n4) {
  int i = blockIdx.x * 256 + threadIdx.x;
  if (i >= n4) return;
  float4 f = ((const float4*)src)[i];
  short4 o;
  o.x = f2bf(f.x); o.y = f2bf(f.y); o.z = f2bf(f.z); o.w = f2bf(f.w);
  ((short4*)dst)[i] = o;
}

// ---------------------------------------------------------------------------
// QKV GEMM (B^T): C[m,n] = sum_k A[m,k]*Bw[n,k]. 256x256 tile, 8 waves
// (2M x 4N, per-wave 128x64), BK=32, 4 LDS slots of 32 KB (A 16K | B 16K),
// counted vmcnt(12): stage kt+3 while computing kt; the post-MFMA barrier
// of iter kt makes restaging slot kt&3 at iter kt+1 race-free. Swizzle
// s(row) = (row^(row>>2))&3 -> <=2-way LDS phases. Epilogue corner-turn in
// two 128-row passes. Q/K: row-major lC (stride 260) -> [B,H,T,D] (K
// pre-scaled by SL2E). V (n0>=2048): transposed lCt (stride 136) -> Vt.
// ---------------------------------------------------------------------------
__global__ __launch_bounds__(512, 2) void gemm_qkv(
    const short* __restrict__ A, const short* __restrict__ Bw,
    short* __restrict__ Qo, short* __restrict__ Ko, short* __restrict__ Vt) {
  const int K = 1024;
  __shared__ short smem[65536];  // 4 slots x 16384 shorts = 128 KB
  const int tid = threadIdx.x;
  const int lane = tid & 63;
  const int wave = tid >> 6;     // 0..7
  const int wr = wave >> 2;      // 0..1  (M half)
  const int wc = wave & 3;       // 0..3  (N quarter)
  const int m0 = blockIdx.y * 256;
  const int n0 = blockIdx.x * 256;
  const int mrow = lane & 15;
  const int kq = lane >> 4;

  f32x4 acc[8][4];
#pragma unroll
  for (int i = 0; i < 8; ++i)
#pragma unroll
    for (int j = 0; j < 4; ++j) acc[i][j] = (f32x4){0.f, 0.f, 0.f, 0.f};

  // stage K-tile it (k0 = it*32) into slot: A 1024 chunks + B 1024 chunks
  auto stage = [&](int it, int slot) {
    short* sb = &smem[slot * 16384];
#pragma unroll
    for (int call = 0; call < 2; ++call) {
      const int cb = call * 512 + wave * 64;
      const int c = cb + lane;
      const int row = c >> 2;                      // 0..255
      const int scol = (c & 3) ^ ((row ^ (row >> 2)) & 3);
      llds16(A + (size_t)(m0 + row) * K + it * 32 + scol * 8, &sb[cb * 8]);
      llds16(Bw + (size_t)(n0 + row) * K + it * 32 + scol * 8, &sb[8192 + cb * 8]);
    }
  };

  auto body = [&](int kt) {
    __builtin_amdgcn_s_barrier();          // slot kt's data landed (vmcnt'd)
    __builtin_amdgcn_sched_barrier(0);
    const short* lA = &smem[(kt & 3) * 16384];
    const short* lB = lA + 8192;
    bf16x8 af[8], bfr[4];
#pragma unroll
    for (int i = 0; i < 8; ++i) {
      const int row = wr * 128 + i * 16 + mrow;
      af[i] = *(const bf16x8*)&lA[row * 32 + (((kq ^ row ^ (row >> 2)) & 3) * 8)];
    }
#pragma unroll
    for (int j = 0; j < 4; ++j) {
      const int row = wc * 64 + j * 16 + mrow;
      bfr[j] = *(const bf16x8*)&lB[row * 32 + (((kq ^ row ^ (row >> 2)) & 3) * 8)];
    }
    __builtin_amdgcn_s_setprio(1);
#pragma unroll
    for (int i = 0; i < 8; ++i)
#pragma unroll
      for (int j = 0; j < 4; ++j)
        acc[i][j] = __builtin_amdgcn_mfma_f32_16x16x32_bf16(af[i], bfr[j], acc[i][j], 0, 0, 0);
    __builtin_amdgcn_s_setprio(0);
    __builtin_amdgcn_sched_barrier(0);
    __builtin_amdgcn_s_barrier();          // all reads of slot kt done
  };

  stage(0, 0); stage(1, 1); stage(2, 2);
  for (int kt = 0; kt < 29; ++kt) {
    stage(kt + 3, (kt + 3) & 3);
    asm volatile("s_waitcnt vmcnt(12)" ::: "memory");  // slot kt complete
    body(kt);
  }
  asm volatile("s_waitcnt vmcnt(8)" ::: "memory");
  body(29);
  asm volatile("s_waitcnt vmcnt(4)" ::: "memory");
  body(30);
  asm volatile("s_waitcnt vmcnt(0)" ::: "memory");
  body(31);

  const int b = m0 >> 11;            // whole tile lies in one batch
  if (n0 < 2048) {
    // Q/K: row-major corner-turn, two 128-row passes (stride 260)
    const float sc_ = ((n0 >> 10) == 1) ? SL2E : 1.0f;
    short* lC = smem;
#pragma unroll 1
    for (int p = 0; p < 2; ++p) {
      if (p) __syncthreads();
      if (wr == p) {
#pragma unroll
        for (int i = 0; i < 8; ++i) {
          const int rl = i * 16 + kq * 4;
#pragma unroll
          for (int j = 0; j < 4; ++j) {
            const int col = wc * 64 + j * 16 + mrow;
#pragma unroll
            for (int r = 0; r < 4; ++r)
              lC[(rl + r) * 260 + col] = f2bf(acc[i][j][r] * sc_);
          }
        }
      }
      __syncthreads();
#pragma unroll
      for (int call = 0; call < 8; ++call) {
        const int cc = call * 512 + tid;
        const int row = cc >> 5;            // 0..127
        const int ch = cc & 31;
        const int t = (m0 + p * 128 + row) & 2047;
        const int o = n0 + ch * 8;
        const int c = o & 1023;
        const int h = c >> 6;
        const int d = c & 63;
        short* dst = (o >> 10) == 0 ? Qo : Ko;
        bf16x8 val = *(const bf16x8*)&lC[row * 260 + ch * 8];
        *(bf16x8*)(dst + ((size_t)(b * 16 + h) * 2048 + t) * 64 + d) = val;
      }
    }
  } else {
    // V: transposed corner-turn (lCt[col][row], stride 136) -> Vt [bh][d][t]
    short* lCt = smem;
#pragma unroll 1
    for (int p = 0; p < 2; ++p) {
      if (p) __syncthreads();
      if (wr == p) {
#pragma unroll
        for (int i = 0; i < 8; ++i) {
          const int rl = i * 16 + kq * 4;
#pragma unroll
          for (int j = 0; j < 4; ++j) {
            const int col = wc * 64 + j * 16 + mrow;
#pragma unroll
            for (int r = 0; r < 4; ++r)
              lCt[col * 136 + rl + r] = f2bf(acc[i][j][r]);
          }
        }
      }
      __syncthreads();
#pragma unroll
      for (int call = 0; call < 8; ++call) {
        const int cc = call * 512 + tid;
        const int col = cc >> 4;            // 0..255
        const int tg = cc & 15;
        const int o = n0 + col;             // 2048..3071
        const int d = o & 63;
        const int h = (o >> 6) & 15;
        const int t = (m0 & 2047) + p * 128 + tg * 8;
        bf16x8 val = *(const bf16x8*)&lCt[col * 136 + tg * 8];
        *(bf16x8*)(Vt + ((size_t)(b * 16 + h) * 64 + d) * 2048 + t) = val;
      }
    }
  }
}

// Out-proj GEMM: M=8192, N=1024, BK=32, double-buffered staging, + bias, fp32.
__global__ __launch_bounds__(256) void gemm_out(
    const short* __restrict__ A, const short* __restrict__ Bw,
    const float* __restrict__ bias, float* __restrict__ Out) {
  const int K = 1024;
  __shared__ short smem[16384];
  const int tid = threadIdx.x;
  const int lane = tid & 63;
  const int wave = tid >> 6;
  const int m0 = blockIdx.y * 128;
  const int n0 = blockIdx.x * 128;
  const int wm = (wave >> 1) * 64;
  const int wn = (wave & 1) * 64;
  const int mrow = lane & 15;
  const int kq = lane >> 4;

  f32x4 acc[4][4];
#pragma unroll
  for (int i = 0; i < 4; ++i)
#pragma unroll
    for (int j = 0; j < 4; ++j) acc[i][j] = (f32x4){0.f, 0.f, 0.f, 0.f};

  auto stage = [&](int it, int buf) {
#pragma unroll
    for (int call = 0; call < 2; ++call) {
      const int cb = call * 256 + wave * 64;
      const int c = cb + lane;
      const int row = c >> 2;
      const int scol = (c & 3) ^ (row & 3);
      llds16(A + (size_t)(m0 + row) * K + it * 32 + scol * 8,
             &smem[buf * 8192 + cb * 8]);
      llds16(Bw + (size_t)(n0 + row) * K + it * 32 + scol * 8,
             &smem[buf * 8192 + 4096 + cb * 8]);
    }
  };

  stage(0, 0);
  __syncthreads();

  for (int it = 0; it < 32; ++it) {
    const int buf = it & 1;
    if (it < 31) stage(it + 1, buf ^ 1);
    const short* lA = &smem[buf * 8192];
    const short* lB = &smem[buf * 8192 + 4096];
    bf16x8 af[4], bfr[4];
#pragma unroll
    for (int i = 0; i < 4; ++i) {
      const int row = wm + i * 16 + mrow;
      af[i] = *(const bf16x8*)&lA[row * 32 + ((kq ^ (row & 3)) * 8)];
    }
#pragma unroll
    for (int j = 0; j < 4; ++j) {
      const int row = wn + j * 16 + mrow;
      bfr[j] = *(const bf16x8*)&lB[row * 32 + ((kq ^ (row & 3)) * 8)];
    }
#pragma unroll
    for (int i = 0; i < 4; ++i)
#pragma unroll
      for (int j = 0; j < 4; ++j)
        acc[i][j] = __builtin_amdgcn_mfma_f32_16x16x32_bf16(af[i], bfr[j], acc[i][j], 0, 0, 0);
    __syncthreads();
  }

#pragma unroll
  for (int i = 0; i < 4; ++i) {
    const int m = m0 + wm + i * 16 + kq * 4;
#pragma unroll
    for (int j = 0; j < 4; ++j) {
      const int n = n0 + wn + j * 16 + mrow;
      const float bb = bias[n];
#pragma unroll
      for (int r = 0; r < 4; ++r)
        Out[(size_t)(m + r) * 1024 + n] = acc[i][j][r] + bb;
    }
  }
}

// ---------------------------------------------------------------------------
// Flash attention R10 (unchanged). Grid (64 bh, 16). TWO q-tiles {bx,31-bx}
// per block (constant 33 seg-iterations). Swapped QK^T (mfma(K,Q)) with
// rho-permuted K rows -> softmax fully in-register, NO cross-lane ops.
// K/V fragments loaded once per kt, shared by both q-tiles. Fixed-max
// softmax (M=15 via MFMA C-init); l via ones-MFMA. Double-buffered staging,
// one barrier per kt. LDS = 32 KB -> 4 blocks/CU.
// ---------------------------------------------------------------------------
__global__ __launch_bounds__(256) void flash_attn(
    const short* __restrict__ Qg, const short* __restrict__ Kg,
    const short* __restrict__ Vtg, short* __restrict__ Og) {
  const int T = 2048;
  __shared__ short lK[2][64 * 64];
  __shared__ short lVt[2][64 * 64];
  const int tid = threadIdx.x;
  const int lane = tid & 63;
  const int wave = tid >> 6;
  const int bh = blockIdx.x;
  const int bx = blockIdx.y;         // 0..15
  const int mrow = lane & 15;
  const int kq = lane >> 4;
  const int swz = mrow & 7;
  const size_t base = (size_t)bh * T * 64;   // Q,K: [bh][t][d]
  const size_t vbase = (size_t)bh * 64 * T;  // Vt:  [bh][d][t]

  const int qt0 = bx;        // active for kt <= qt0
  const int qt1 = 31 - bx;   // active for all kt (ktmax = qt1)

  const bf16x8 ones = {0x3F80, 0x3F80, 0x3F80, 0x3F80, 0x3F80, 0x3F80, 0x3F80, 0x3F80};

  bf16x8 aq0_0, aq1_0, aq0_1, aq1_1;
  {
    const short* qp0 = Qg + base + (size_t)(qt0 * 64 + wave * 16 + mrow) * 64 + kq * 8;
    aq0_0 = *(const bf16x8*)qp0;
    aq1_0 = *(const bf16x8*)(qp0 + 32);
    const short* qp1 = Qg + base + (size_t)(qt1 * 64 + wave * 16 + mrow) * 64 + kq * 8;
    aq0_1 = *(const bf16x8*)qp1;
    aq1_1 = *(const bf16x8*)(qp1 + 32);
  }

  f32x4 acc0[4], acc1[4], lac0, lac1;
  lac0 = (f32x4){0.f, 0.f, 0.f, 0.f};
  lac1 = (f32x4){0.f, 0.f, 0.f, 0.f};
#pragma unroll
  for (int jd = 0; jd < 4; ++jd) {
    acc0[jd] = (f32x4){0.f, 0.f, 0.f, 0.f};
    acc1[jd] = (f32x4){0.f, 0.f, 0.f, 0.f};
  }

  auto stage = [&](int nt, int buf) {
#pragma unroll
    for (int call = 0; call < 2; ++call) {
      const int cb = call * 256 + wave * 64;
      const int c = cb + lane;
      const int row = c >> 3;
      const int scol = (c & 7) ^ (row & 7);
      // K row permutation rho: LDS row p holds key with bit-permuted index
      // (b5,b4,b3,b2 -> b5,b3,b2,b4) so the in-lane P pack IS the PV A-frag.
      const int grow = (row & 0x23) | ((row & 0x0C) << 1) | ((row & 0x10) >> 2);
      llds16(Kg + base + (size_t)(nt * 64 + grow) * 64 + scol * 8, &lK[buf][cb * 8]);
      llds16(Vtg + vbase + (size_t)row * T + nt * 64 + scol * 8, &lVt[buf][cb * 8]);
    }
  };

  stage(0, 0);
  __syncthreads();

  auto seg = [&](auto Aa, const short* K_, const short* Vt_, int kt) {
    constexpr bool ACT0 = decltype(Aa)::value;
    // ---- QK^T (swapped: A = K rows -> D row = K-LDS position, col = q) ----
    f32x4 sc0[4], sc1[4];
#pragma unroll
    for (int j = 0; j < 4; ++j) {
      const short* krow = &K_[(j * 16 + mrow) * 64];
      bf16x8 kb0 = *(const bf16x8*)&krow[(kq ^ swz) * 8];
      bf16x8 kb1 = *(const bf16x8*)&krow[((4 + kq) ^ swz) * 8];
      __builtin_amdgcn_s_setprio(1);
      f32x4 ss = (f32x4){-FIXED_M, -FIXED_M, -FIXED_M, -FIXED_M};
      ss = __builtin_amdgcn_mfma_f32_16x16x32_bf16(kb0, aq0_1, ss, 0, 0, 0);
      ss = __builtin_amdgcn_mfma_f32_16x16x32_bf16(kb1, aq1_1, ss, 0, 0, 0);
      sc1[j] = ss;
      if constexpr (ACT0) {
        f32x4 s2 = (f32x4){-FIXED_M, -FIXED_M, -FIXED_M, -FIXED_M};
        s2 = __builtin_amdgcn_mfma_f32_16x16x32_bf16(kb0, aq0_0, s2, 0, 0, 0);
        s2 = __builtin_amdgcn_mfma_f32_16x16x32_bf16(kb1, aq1_0, s2, 0, 0, 0);
        sc0[j] = s2;
      }
      __builtin_amdgcn_s_setprio(0);
    }

    // ---- causal masks (diagonal tiles). sc[j][r] is key
    // kt*64 + 32*(j>>1) + 8*kq + 4*(j&1) + r under rho. ----
    if (kt == qt1) {
      const int qcol = qt1 * 64 + wave * 16 + mrow;
#pragma unroll
      for (int j = 0; j < 4; ++j) {
        const int keyb = kt * 64 + ((j & 2) << 4) + (kq << 3) + ((j & 1) << 2);
#pragma unroll
        for (int r = 0; r < 4; ++r)
          if (keyb + r > qcol) sc1[j][r] = -1e30f;
      }
    }
    if constexpr (ACT0) {
      if (kt == qt0) {
        const int qcol = qt0 * 64 + wave * 16 + mrow;
#pragma unroll
        for (int j = 0; j < 4; ++j) {
          const int keyb = kt * 64 + ((j & 2) << 4) + (kq << 3) + ((j & 1) << 2);
#pragma unroll
          for (int r = 0; r < 4; ++r)
            if (keyb + r > qcol) sc0[j][r] = -1e30f;
        }
      }
    }

    // ---- softmax: exp2 + direct in-lane pack (no shuffles) ----
    bf16x8 pa0_1, pa1_1, pa0_0, pa1_0;
    softmax_pack(sc1, pa0_1, pa1_1);
    lac1 = __builtin_amdgcn_mfma_f32_16x16x32_bf16(pa0_1, ones, lac1, 0, 0, 0);
    lac1 = __builtin_amdgcn_mfma_f32_16x16x32_bf16(pa1_1, ones, lac1, 0, 0, 0);
    if constexpr (ACT0) {
      softmax_pack(sc0, pa0_0, pa1_0);
      lac0 = __builtin_amdgcn_mfma_f32_16x16x32_bf16(pa0_0, ones, lac0, 0, 0, 0);
      lac0 = __builtin_amdgcn_mfma_f32_16x16x32_bf16(pa1_0, ones, lac0, 0, 0, 0);
    }

    // ---- PV: V fragments loaded once, shared by both q-tiles ----
#pragma unroll
    for (int jd = 0; jd < 4; ++jd) {
      const short* vrow = &Vt_[(jd * 16 + mrow) * 64];
      bf16x8 vb0 = *(const bf16x8*)&vrow[(kq ^ swz) * 8];
      bf16x8 vb1 = *(const bf16x8*)&vrow[((4 + kq) ^ swz) * 8];
      __builtin_amdgcn_s_setprio(1);
      acc1[jd] = __builtin_amdgcn_mfma_f32_16x16x32_bf16(pa0_1, vb0, acc1[jd], 0, 0, 0);
      acc1[jd] = __builtin_amdgcn_mfma_f32_16x16x32_bf16(pa1_1, vb1, acc1[jd], 0, 0, 0);
      if constexpr (ACT0) {
        acc0[jd] = __builtin_amdgcn_mfma_f32_16x16x32_bf16(pa0_0, vb0, acc0[jd], 0, 0, 0);
        acc0[jd] = __builtin_amdgcn_mfma_f32_16x16x32_bf16(pa1_0, vb1, acc0[jd], 0, 0, 0);
      }
      __builtin_amdgcn_s_setprio(0);
    }
  };

  for (int kt = 0; kt <= qt1; ++kt) {
    const int bcur = kt & 1;
    if (kt < qt1) stage(kt + 1, bcur ^ 1);
    if (kt <= qt0) seg(BoolC<true>{}, lK[bcur], lVt[bcur], kt);
    else           seg(BoolC<false>{}, lK[bcur], lVt[bcur], kt);
    __syncthreads();
  }

  const int b = bh >> 4;
  const int h = bh & 15;
#pragma unroll
  for (int r = 0; r < 4; ++r) {
    const float inv0 = 1.0f / lac0[r];
    const int t0 = qt0 * 64 + wave * 16 + kq * 4 + r;
#pragma unroll
    for (int jd = 0; jd < 4; ++jd) {
      const int col = h * 64 + jd * 16 + mrow;
      Og[((size_t)b * 2048 + t0) * 1024 + col] = f2bf(acc0[jd][r] * inv0);
    }
    const float inv1 = 1.0f / lac1[r];
    const int t1 = qt1 * 64 + wave * 16 + kq * 4 + r;
#pragma unroll
    for (int jd = 0; jd < 4; ++jd) {
      const int col = h * 64 + jd * 16 + mrow;
      Og[((size_t)b * 2048 + t1) * 1024 + col] = f2bf(acc1[jd][r] * inv1);
    }
  }
}

extern "C" void kernel_launch(void* const* d_in, const int* in_sizes, int n_in,
                              void* d_out, int out_size, void* d_ws, size_t ws_size,
                              hipStream_t stream) {
  const float* x = (const float*)d_in[0];
  const float* w_qkv = (const float*)d_in[1];
  const float* w_out = (const float*)d_in[2];
  const float* b_out = (const float*)d_in[3];
  float* out = (float*)d_out;

  char* ws = (char*)d_ws;
  const size_t NX = 8192ull * 1024;
  const size_t NWQ = 3072ull * 1024;
  const size_t NWO = 1024ull * 1024;
  const size_t NQ = 64ull * 2048 * 64;
  size_t off = 0;
  short* xb    = (short*)(ws + off); off += NX * 2;
  short* wqkvb = (short*)(ws + off); off += NWQ * 2;
  short* woutb = (short*)(ws + off); off += NWO * 2;
  short* q     = (short*)(ws + off); off += NQ * 2;
  short* k     = (short*)(ws + off); off += NQ * 2;
  short* vt    = (short*)(ws + off); off += NQ * 2;  // V stored transposed [bh][d][t]
  short* attb  = (short*)(ws + off); off += NX * 2;
  if (off > ws_size) return;

  cast_f32_to_bf16<<<(int)(NX / 4 / 256), 256, 0, stream>>>(x, xb, (int)(NX / 4));
  cast_f32_to_bf16<<<(int)(NWQ / 4 / 256), 256, 0, stream>>>(w_qkv, wqkvb, (int)(NWQ / 4));
  cast_f32_to_bf16<<<(int)(NWO / 4 / 256), 256, 0, stream>>>(w_out, woutb, (int)(NWO / 4));
  gemm_qkv<<<dim3(12, 32), 512, 0, stream>>>(xb, wqkvb, q, k, vt);
  flash_attn<<<dim3(64, 16), 256, 0, stream>>>(q, k, vt, attb);
  gemm_out<<<dim3(8, 64), 256, 0, stream>>>(attb, woutb, b_out, out);
}

// Round 4
// 254.605 us; speedup vs baseline: 1.0323x; 1.0323x over previous
//
#include <hip/hip_runtime.h>
#include <stdint.h>

// MultiHeadAttention: B=4, T=2048, C=1024, H=16, D=64, causal, scale=1/8.
// R12: revert gemm_qkv to the proven 128x128 / 4-blocks-per-CU structure
// (R11's 256^2 1-block/CU regressed: occupancy 15%, 2 serial rounds).
// Keep R11's conflict-free swizzle s(row) = (row^(row>>2))&3 in BOTH GEMM
// bodies: every 8-lane octet of a ds_read_b128 now covers all 32 banks
// exactly once (old (row&3) swizzle was 2-way per octet -> 6.5M conflicts).
// Casts merged into one launch. flash_attn = R10 (rho-relabeled in-register
// softmax) unchanged.
//
// MFMA 16x16x32 bf16 layouts:
//   A frag: m = lane&15, k = (lane>>4)*8 + j
//   B frag: n = lane&15, k = (lane>>4)*8 + j
//   C/D:    col = lane&15, row = (lane>>4)*4 + reg

typedef __attribute__((ext_vector_type(8))) short bf16x8;
typedef __attribute__((ext_vector_type(4))) float f32x4;

#define EXP2F(x) __builtin_amdgcn_exp2f(x)
#define SL2E 0.18033688011112042f  /* 0.125 * log2(e) */
#define FIXED_M 15.0f

template <bool B> struct BoolC { static constexpr bool value = B; };

__device__ __forceinline__ short f2bf(float f) {
  union { float f; unsigned u; } c; c.f = f;
  unsigned u = c.u;
  unsigned r = (u + 0x7fffu + ((u >> 16) & 1u)) >> 16;
  return (short)(unsigned short)r;
}

// sc[j][r] = S at LDS K position 16j + 4kq + r, q = mrow (log2 units).
// Direct in-lane pack -> PV A-fragments (rho relabeling, see flash_attn).
__device__ __forceinline__ void softmax_pack(const f32x4* sc, bf16x8& pa0, bf16x8& pa1) {
  union U { int i[4]; bf16x8 v; };
  U u0, u1;
#pragma unroll
  for (int j = 0; j < 4; ++j) {
    float p0 = EXP2F(sc[j][0]);
    float p1 = EXP2F(sc[j][1]);
    float p2 = EXP2F(sc[j][2]);
    float p3 = EXP2F(sc[j][3]);
    int w0, w1;
    asm("v_cvt_pk_bf16_f32 %0, %1, %2" : "=v"(w0) : "v"(p0), "v"(p1));
    asm("v_cvt_pk_bf16_f32 %0, %1, %2" : "=v"(w1) : "v"(p2), "v"(p3));
    if (j < 2) { u0.i[j * 2] = w0; u0.i[j * 2 + 1] = w1; }
    else       { u1.i[(j - 2) * 2] = w0; u1.i[(j - 2) * 2 + 1] = w1; }
  }
  pa0 = u0.v;
  pa1 = u1.v;
}

// async 16B global -> LDS (dest = wave-uniform base + lane*16)
__device__ __forceinline__ void llds16(const short* g, short* l) {
  __builtin_amdgcn_global_load_lds(
      (const __attribute__((address_space(1))) unsigned int*)g,
      (__attribute__((address_space(3))) unsigned int*)l, 16, 0, 0);
}

// One launch for all three f32->bf16 casts. Ranges are exact multiples of
// 256 blocks: x = 8192, w_qkv = 3072, w_out = 1024.
__global__ __launch_bounds__(256) void cast_all(
    const float* __restrict__ x, const float* __restrict__ wq,
    const float* __restrict__ wo, short* __restrict__ xb,
    short* __restrict__ wqb, short* __restrict__ wob) {
  const int b = blockIdx.x;
  const float* src;
  short* dst;
  int idx;
  if (b < 8192)        { src = x;  dst = xb;  idx = b * 256 + threadIdx.x; }
  else if (b < 11264)  { src = wq; dst = wqb; idx = (b - 8192) * 256 + threadIdx.x; }
  else                 { src = wo; dst = wob; idx = (b - 11264) * 256 + threadIdx.x; }
  float4 f = ((const float4*)src)[idx];
  short4 o;
  o.x = f2bf(f.x); o.y = f2bf(f.y); o.z = f2bf(f.z); o.w = f2bf(f.w);
  ((short4*)dst)[idx] = o;
}

// ---------------------------------------------------------------------------
// QKV GEMM (B^T): C[m,n] = sum_k A[m,k]*Bw[n,k]. 128x128 tile, BK=32,
// DOUBLE-BUFFERED staging (1 barrier/iter), conflict-free XOR swizzle
// (g(row) = (row^(row>>2))&3, applied to the GLOBAL source address so the
// LDS dest stays linear; read side XORs the same involution), LDS union
// with corner-turn epilogue (34 KB -> 4 blocks/CU). Q/K: row-major lC ->
// [B,H,T,D] (K pre-scaled by SL2E). V (n0>=2048): transposed lCt -> Vt.
// ---------------------------------------------------------------------------
__global__ __launch_bounds__(256) void gemm_qkv(
    const short* __restrict__ A, const short* __restrict__ Bw,
    short* __restrict__ Qo, short* __restrict__ Ko, short* __restrict__ Vt) {
  const int K = 1024;
  __shared__ short smem[17408];  // [buf0: A 4096|B 4096][buf1: A 4096|B 4096] | lC/lCt
  const int tid = threadIdx.x;
  const int lane = tid & 63;
  const int wave = tid >> 6;
  const int m0 = blockIdx.y * 128;
  const int n0 = blockIdx.x * 128;
  const int wm = (wave >> 1) * 64;
  const int wn = (wave & 1) * 64;
  const int mrow = lane & 15;
  const int kq = lane >> 4;

  f32x4 acc[4][4];
#pragma unroll
  for (int i = 0; i < 4; ++i)
#pragma unroll
    for (int j = 0; j < 4; ++j) acc[i][j] = (f32x4){0.f, 0.f, 0.f, 0.f};

  // stage tile it (k0 = it*32) into buffer buf: 512 chunks of 8 shorts each
  auto stage = [&](int it, int buf) {
#pragma unroll
    for (int call = 0; call < 2; ++call) {
      const int cb = call * 256 + wave * 64;
      const int c = cb + lane;
      const int row = c >> 2;
      const int scol = (c & 3) ^ ((row ^ (row >> 2)) & 3);
      llds16(A + (size_t)(m0 + row) * K + it * 32 + scol * 8,
             &smem[buf * 8192 + cb * 8]);
      llds16(Bw + (size_t)(n0 + row) * K + it * 32 + scol * 8,
             &smem[buf * 8192 + 4096 + cb * 8]);
    }
  };

  stage(0, 0);
  __syncthreads();

  for (int it = 0; it < 32; ++it) {
    const int buf = it & 1;
    if (it < 31) stage(it + 1, buf ^ 1);
    const short* lA = &smem[buf * 8192];
    const short* lB = &smem[buf * 8192 + 4096];
    bf16x8 af[4], bfr[4];
#pragma unroll
    for (int i = 0; i < 4; ++i) {
      const int row = wm + i * 16 + mrow;
      af[i] = *(const bf16x8*)&lA[row * 32 + (((kq ^ row ^ (row >> 2)) & 3) * 8)];
    }
#pragma unroll
    for (int j = 0; j < 4; ++j) {
      const int row = wn + j * 16 + mrow;
      bfr[j] = *(const bf16x8*)&lB[row * 32 + (((kq ^ row ^ (row >> 2)) & 3) * 8)];
    }
#pragma unroll
    for (int i = 0; i < 4; ++i)
#pragma unroll
      for (int j = 0; j < 4; ++j)
        acc[i][j] = __builtin_amdgcn_mfma_f32_16x16x32_bf16(af[i], bfr[j], acc[i][j], 0, 0, 0);
    __syncthreads();
  }

  const int b = m0 >> 11;            // whole tile lies in one batch
  if (n0 < 2048) {
    // Q/K block: row-major corner-turn (stride 132), coalesced 16B stores
    short* lC = smem;
#pragma unroll
    for (int i = 0; i < 4; ++i) {
      const int row = wm + i * 16 + kq * 4;
#pragma unroll
      for (int j = 0; j < 4; ++j) {
        const int col = wn + j * 16 + mrow;
        const float sc_ = (((n0 + col) >> 10) == 1) ? SL2E : 1.0f;
#pragma unroll
        for (int r = 0; r < 4; ++r)
          lC[(row + r) * 132 + col] = f2bf(acc[i][j][r] * sc_);
      }
    }
    __syncthreads();
#pragma unroll
    for (int call = 0; call < 8; ++call) {
      const int cc = call * 256 + tid;
      const int row = cc >> 4;
      const int t = (m0 + row) & 2047;
      const int o = n0 + (cc & 15) * 8;
      const int c = o & 1023;
      const int h = c >> 6;
      const int d = c & 63;
      short* dst = (o >> 10) == 0 ? Qo : Ko;
      bf16x8 val = *(const bf16x8*)&lC[row * 132 + (cc & 15) * 8];
      *(bf16x8*)(dst + ((size_t)(b * 16 + h) * 2048 + t) * 64 + d) = val;
    }
  } else {
    // V block: transposed corner-turn (lCt[col][row], stride 136) -> Vt [bh][d][t]
    short* lCt = smem;
#pragma unroll
    for (int i = 0; i < 4; ++i) {
      const int row = wm + i * 16 + kq * 4;
#pragma unroll
      for (int j = 0; j < 4; ++j) {
        const int col = wn + j * 16 + mrow;
#pragma unroll
        for (int r = 0; r < 4; ++r)
          lCt[col * 136 + row + r] = f2bf(acc[i][j][r]);
      }
    }
    __syncthreads();
#pragma unroll
    for (int call = 0; call < 8; ++call) {
      const int cc = call * 256 + tid;
      const int col = cc >> 4;
      const int tg = cc & 15;
      const int o = n0 + col;           // 2048..3071
      const int d = o & 63;
      const int h = (o >> 6) & 15;
      const int t = (m0 & 2047) + tg * 8;   // batch offset lives in bh, not t
      bf16x8 val = *(const bf16x8*)&lCt[col * 136 + tg * 8];
      *(bf16x8*)(Vt + ((size_t)(b * 16 + h) * 64 + d) * 2048 + t) = val;
    }
  }
}

// Out-proj GEMM: M=8192, N=1024, BK=32, double-buffered staging, + bias, fp32.
// Same conflict-free swizzle as gemm_qkv.
__global__ __launch_bounds__(256) void gemm_out(
    const short* __restrict__ A, const short* __restrict__ Bw,
    const float* __restrict__ bias, float* __restrict__ Out) {
  const int K = 1024;
  __shared__ short smem[16384];
  const int tid = threadIdx.x;
  const int lane = tid & 63;
  const int wave = tid >> 6;
  const int m0 = blockIdx.y * 128;
  const int n0 = blockIdx.x * 128;
  const int wm = (wave >> 1) * 64;
  const int wn = (wave & 1) * 64;
  const int mrow = lane & 15;
  const int kq = lane >> 4;

  f32x4 acc[4][4];
#pragma unroll
  for (int i = 0; i < 4; ++i)
#pragma unroll
    for (int j = 0; j < 4; ++j) acc[i][j] = (f32x4){0.f, 0.f, 0.f, 0.f};

  auto stage = [&](int it, int buf) {
#pragma unroll
    for (int call = 0; call < 2; ++call) {
      const int cb = call * 256 + wave * 64;
      const int c = cb + lane;
      const int row = c >> 2;
      const int scol = (c & 3) ^ ((row ^ (row >> 2)) & 3);
      llds16(A + (size_t)(m0 + row) * K + it * 32 + scol * 8,
             &smem[buf * 8192 + cb * 8]);
      llds16(Bw + (size_t)(n0 + row) * K + it * 32 + scol * 8,
             &smem[buf * 8192 + 4096 + cb * 8]);
    }
  };

  stage(0, 0);
  __syncthreads();

  for (int it = 0; it < 32; ++it) {
    const int buf = it & 1;
    if (it < 31) stage(it + 1, buf ^ 1);
    const short* lA = &smem[buf * 8192];
    const short* lB = &smem[buf * 8192 + 4096];
    bf16x8 af[4], bfr[4];
#pragma unroll
    for (int i = 0; i < 4; ++i) {
      const int row = wm + i * 16 + mrow;
      af[i] = *(const bf16x8*)&lA[row * 32 + (((kq ^ row ^ (row >> 2)) & 3) * 8)];
    }
#pragma unroll
    for (int j = 0; j < 4; ++j) {
      const int row = wn + j * 16 + mrow;
      bfr[j] = *(const bf16x8*)&lB[row * 32 + (((kq ^ row ^ (row >> 2)) & 3) * 8)];
    }
#pragma unroll
    for (int i = 0; i < 4; ++i)
#pragma unroll
      for (int j = 0; j < 4; ++j)
        acc[i][j] = __builtin_amdgcn_mfma_f32_16x16x32_bf16(af[i], bfr[j], acc[i][j], 0, 0, 0);
    __syncthreads();
  }

#pragma unroll
  for (int i = 0; i < 4; ++i) {
    const int m = m0 + wm + i * 16 + kq * 4;
#pragma unroll
    for (int j = 0; j < 4; ++j) {
      const int n = n0 + wn + j * 16 + mrow;
      const float bb = bias[n];
#pragma unroll
      for (int r = 0; r < 4; ++r)
        Out[(size_t)(m + r) * 1024 + n] = acc[i][j][r] + bb;
    }
  }
}

// ---------------------------------------------------------------------------
// Flash attention R10 (unchanged). Grid (64 bh, 16). TWO q-tiles {bx,31-bx}
// per block (constant 33 seg-iterations). Swapped QK^T (mfma(K,Q)) with
// rho-permuted K rows -> softmax fully in-register, NO cross-lane ops.
// K/V fragments loaded once per kt, shared by both q-tiles. Fixed-max
// softmax (M=15 via MFMA C-init); l via ones-MFMA. Double-buffered staging,
// one barrier per kt. LDS = 32 KB -> 4 blocks/CU.
// ---------------------------------------------------------------------------
__global__ __launch_bounds__(256) void flash_attn(
    const short* __restrict__ Qg, const short* __restrict__ Kg,
    const short* __restrict__ Vtg, short* __restrict__ Og) {
  const int T = 2048;
  __shared__ short lK[2][64 * 64];
  __shared__ short lVt[2][64 * 64];
  const int tid = threadIdx.x;
  const int lane = tid & 63;
  const int wave = tid >> 6;
  const int bh = blockIdx.x;
  const int bx = blockIdx.y;         // 0..15
  const int mrow = lane & 15;
  const int kq = lane >> 4;
  const int swz = mrow & 7;
  const size_t base = (size_t)bh * T * 64;   // Q,K: [bh][t][d]
  const size_t vbase = (size_t)bh * 64 * T;  // Vt:  [bh][d][t]

  const int qt0 = bx;        // active for kt <= qt0
  const int qt1 = 31 - bx;   // active for all kt (ktmax = qt1)

  const bf16x8 ones = {0x3F80, 0x3F80, 0x3F80, 0x3F80, 0x3F80, 0x3F80, 0x3F80, 0x3F80};

  bf16x8 aq0_0, aq1_0, aq0_1, aq1_1;
  {
    const short* qp0 = Qg + base + (size_t)(qt0 * 64 + wave * 16 + mrow) * 64 + kq * 8;
    aq0_0 = *(const bf16x8*)qp0;
    aq1_0 = *(const bf16x8*)(qp0 + 32);
    const short* qp1 = Qg + base + (size_t)(qt1 * 64 + wave * 16 + mrow) * 64 + kq * 8;
    aq0_1 = *(const bf16x8*)qp1;
    aq1_1 = *(const bf16x8*)(qp1 + 32);
  }

  f32x4 acc0[4], acc1[4], lac0, lac1;
  lac0 = (f32x4){0.f, 0.f, 0.f, 0.f};
  lac1 = (f32x4){0.f, 0.f, 0.f, 0.f};
#pragma unroll
  for (int jd = 0; jd < 4; ++jd) {
    acc0[jd] = (f32x4){0.f, 0.f, 0.f, 0.f};
    acc1[jd] = (f32x4){0.f, 0.f, 0.f, 0.f};
  }

  auto stage = [&](int nt, int buf) {
#pragma unroll
    for (int call = 0; call < 2; ++call) {
      const int cb = call * 256 + wave * 64;
      const int c = cb + lane;
      const int row = c >> 3;
      const int scol = (c & 7) ^ (row & 7);
      // K row permutation rho: LDS row p holds key with bit-permuted index
      // (b5,b4,b3,b2 -> b5,b3,b2,b4) so the in-lane P pack IS the PV A-frag.
      const int grow = (row & 0x23) | ((row & 0x0C) << 1) | ((row & 0x10) >> 2);
      llds16(Kg + base + (size_t)(nt * 64 + grow) * 64 + scol * 8, &lK[buf][cb * 8]);
      llds16(Vtg + vbase + (size_t)row * T + nt * 64 + scol * 8, &lVt[buf][cb * 8]);
    }
  };

  stage(0, 0);
  __syncthreads();

  auto seg = [&](auto Aa, const short* K_, const short* Vt_, int kt) {
    constexpr bool ACT0 = decltype(Aa)::value;
    // ---- QK^T (swapped: A = K rows -> D row = K-LDS position, col = q) ----
    f32x4 sc0[4], sc1[4];
#pragma unroll
    for (int j = 0; j < 4; ++j) {
      const short* krow = &K_[(j * 16 + mrow) * 64];
      bf16x8 kb0 = *(const bf16x8*)&krow[(kq ^ swz) * 8];
      bf16x8 kb1 = *(const bf16x8*)&krow[((4 + kq) ^ swz) * 8];
      __builtin_amdgcn_s_setprio(1);
      f32x4 ss = (f32x4){-FIXED_M, -FIXED_M, -FIXED_M, -FIXED_M};
      ss = __builtin_amdgcn_mfma_f32_16x16x32_bf16(kb0, aq0_1, ss, 0, 0, 0);
      ss = __builtin_amdgcn_mfma_f32_16x16x32_bf16(kb1, aq1_1, ss, 0, 0, 0);
      sc1[j] = ss;
      if constexpr (ACT0) {
        f32x4 s2 = (f32x4){-FIXED_M, -FIXED_M, -FIXED_M, -FIXED_M};
        s2 = __builtin_amdgcn_mfma_f32_16x16x32_bf16(kb0, aq0_0, s2, 0, 0, 0);
        s2 = __builtin_amdgcn_mfma_f32_16x16x32_bf16(kb1, aq1_0, s2, 0, 0, 0);
        sc0[j] = s2;
      }
      __builtin_amdgcn_s_setprio(0);
    }

    // ---- causal masks (diagonal tiles). sc[j][r] is key
    // kt*64 + 32*(j>>1) + 8*kq + 4*(j&1) + r under rho. ----
    if (kt == qt1) {
      const int qcol = qt1 * 64 + wave * 16 + mrow;
#pragma unroll
      for (int j = 0; j < 4; ++j) {
        const int keyb = kt * 64 + ((j & 2) << 4) + (kq << 3) + ((j & 1) << 2);
#pragma unroll
        for (int r = 0; r < 4; ++r)
          if (keyb + r > qcol) sc1[j][r] = -1e30f;
      }
    }
    if constexpr (ACT0) {
      if (kt == qt0) {
        const int qcol = qt0 * 64 + wave * 16 + mrow;
#pragma unroll
        for (int j = 0; j < 4; ++j) {
          const int keyb = kt * 64 + ((j & 2) << 4) + (kq << 3) + ((j & 1) << 2);
#pragma unroll
          for (int r = 0; r < 4; ++r)
            if (keyb + r > qcol) sc0[j][r] = -1e30f;
        }
      }
    }

    // ---- softmax: exp2 + direct in-lane pack (no shuffles) ----
    bf16x8 pa0_1, pa1_1, pa0_0, pa1_0;
    softmax_pack(sc1, pa0_1, pa1_1);
    lac1 = __builtin_amdgcn_mfma_f32_16x16x32_bf16(pa0_1, ones, lac1, 0, 0, 0);
    lac1 = __builtin_amdgcn_mfma_f32_16x16x32_bf16(pa1_1, ones, lac1, 0, 0, 0);
    if constexpr (ACT0) {
      softmax_pack(sc0, pa0_0, pa1_0);
      lac0 = __builtin_amdgcn_mfma_f32_16x16x32_bf16(pa0_0, ones, lac0, 0, 0, 0);
      lac0 = __builtin_amdgcn_mfma_f32_16x16x32_bf16(pa1_0, ones, lac0, 0, 0, 0);
    }

    // ---- PV: V fragments loaded once, shared by both q-tiles ----
#pragma unroll
    for (int jd = 0; jd < 4; ++jd) {
      const short* vrow = &Vt_[(jd * 16 + mrow) * 64];
      bf16x8 vb0 = *(const bf16x8*)&vrow[(kq ^ swz) * 8];
      bf16x8 vb1 = *(const bf16x8*)&vrow[((4 + kq) ^ swz) * 8];
      __builtin_amdgcn_s_setprio(1);
      acc1[jd] = __builtin_amdgcn_mfma_f32_16x16x32_bf16(pa0_1, vb0, acc1[jd], 0, 0, 0);
      acc1[jd] = __builtin_amdgcn_mfma_f32_16x16x32_bf16(pa1_1, vb1, acc1[jd], 0, 0, 0);
      if constexpr (ACT0) {
        acc0[jd] = __builtin_amdgcn_mfma_f32_16x16x32_bf16(pa0_0, vb0, acc0[jd], 0, 0, 0);
        acc0[jd] = __builtin_amdgcn_mfma_f32_16x16x32_bf16(pa1_0, vb1, acc0[jd], 0, 0, 0);
      }
      __builtin_amdgcn_s_setprio(0);
    }
  };

  for (int kt = 0; kt <= qt1; ++kt) {
    const int bcur = kt & 1;
    if (kt < qt1) stage(kt + 1, bcur ^ 1);
    if (kt <= qt0) seg(BoolC<true>{}, lK[bcur], lVt[bcur], kt);
    else           seg(BoolC<false>{}, lK[bcur], lVt[bcur], kt);
    __syncthreads();
  }

  const int b = bh >> 4;
  const int h = bh & 15;
#pragma unroll
  for (int r = 0; r < 4; ++r) {
    const float inv0 = 1.0f / lac0[r];
    const int t0 = qt0 * 64 + wave * 16 + kq * 4 + r;
#pragma unroll
    for (int jd = 0; jd < 4; ++jd) {
      const int col = h * 64 + jd * 16 + mrow;
      Og[((size_t)b * 2048 + t0) * 1024 + col] = f2bf(acc0[jd][r] * inv0);
    }
    const float inv1 = 1.0f / lac1[r];
    const int t1 = qt1 * 64 + wave * 16 + kq * 4 + r;
#pragma unroll
    for (int jd = 0; jd < 4; ++jd) {
      const int col = h * 64 + jd * 16 + mrow;
      Og[((size_t)b * 2048 + t1) * 1024 + col] = f2bf(acc1[jd][r] * inv1);
    }
  }
}

extern "C" void kernel_launch(void* const* d_in, const int* in_sizes, int n_in,
                              void* d_out, int out_size, void* d_ws, size_t ws_size,
                              hipStream_t stream) {
  const float* x = (const float*)d_in[0];
  const float* w_qkv = (const float*)d_in[1];
  const float* w_out = (const float*)d_in[2];
  const float* b_out = (const float*)d_in[3];
  float* out = (float*)d_out;

  char* ws = (char*)d_ws;
  const size_t NX = 8192ull * 1024;
  const size_t NWQ = 3072ull * 1024;
  const size_t NWO = 1024ull * 1024;
  const size_t NQ = 64ull * 2048 * 64;
  size_t off = 0;
  short* xb    = (short*)(ws + off); off += NX * 2;
  short* wqkvb = (short*)(ws + off); off += NWQ * 2;
  short* woutb = (short*)(ws + off); off += NWO * 2;
  short* q     = (short*)(ws + off); off += NQ * 2;
  short* k     = (short*)(ws + off); off += NQ * 2;
  short* vt    = (short*)(ws + off); off += NQ * 2;  // V stored transposed [bh][d][t]
  short* attb  = (short*)(ws + off); off += NX * 2;
  if (off > ws_size) return;

  cast_all<<<12288, 256, 0, stream>>>(x, w_qkv, w_out, xb, wqkvb, woutb);
  gemm_qkv<<<dim3(24, 64), 256, 0, stream>>>(xb, wqkvb, q, k, vt);
  flash_attn<<<dim3(64, 16), 256, 0, stream>>>(q, k, vt, attb);
  gemm_out<<<dim3(8, 64), 256, 0, stream>>>(attb, woutb, b_out, out);
}

// Round 5
// 248.474 us; speedup vs baseline: 1.0578x; 1.0247x over previous
//
#include <hip/hip_runtime.h>
#include <stdint.h>

// MultiHeadAttention: B=4, T=2048, C=1024, H=16, D=64, causal, scale=1/8.
// R13: gemm_qkv -> true 8-phase counted-vmcnt schedule (T3+T4+T5):
// BM=256 BN=128 BK=64, 512 thr (8 waves, 4Mx2N, per-wave 64x64), LDS 96KB
// double-buffered. Per K-tile 4 phases: {ds_read subfrags | issue 1-2
// global_load_lds of t+1 -> s_barrier -> lgkmcnt(0)+sched_barrier ->
// setprio(1) 8xMFMA setprio(0) -> s_barrier}; vmcnt(0) once per tile
// boundary (in-flight = next tile's 6 loads exactly). Grid (24,32)=768
// blocks = exactly 3.0 rounds at 1 block/CU (R11's 1.5-round quantization
// fixed). Staging swizzle (c&7)^(row&7) on GLOBAL source, same XOR on
// reads (row stride 128B would otherwise be 32-way). Epilogue: proven
// corner-turn re-strided for 256x128, single pass.
// flash_attn (R10) / gemm_out / cast_all unchanged.
//
// MFMA 16x16x32 bf16 layouts:
//   A frag: m = lane&15, k = (lane>>4)*8 + j
//   B frag: n = lane&15, k = (lane>>4)*8 + j
//   C/D:    col = lane&15, row = (lane>>4)*4 + reg

typedef __attribute__((ext_vector_type(8))) short bf16x8;
typedef __attribute__((ext_vector_type(4))) float f32x4;

#define EXP2F(x) __builtin_amdgcn_exp2f(x)
#define SL2E 0.18033688011112042f  /* 0.125 * log2(e) */
#define FIXED_M 15.0f

template <bool B> struct BoolC { static constexpr bool value = B; };

__device__ __forceinline__ short f2bf(float f) {
  union { float f; unsigned u; } c; c.f = f;
  unsigned u = c.u;
  unsigned r = (u + 0x7fffu + ((u >> 16) & 1u)) >> 16;
  return (short)(unsigned short)r;
}

// sc[j][r] = S at LDS K position 16j + 4kq + r, q = mrow (log2 units).
// Direct in-lane pack -> PV A-fragments (rho relabeling, see flash_attn).
__device__ __forceinline__ void softmax_pack(const f32x4* sc, bf16x8& pa0, bf16x8& pa1) {
  union U { int i[4]; bf16x8 v; };
  U u0, u1;
#pragma unroll
  for (int j = 0; j < 4; ++j) {
    float p0 = EXP2F(sc[j][0]);
    float p1 = EXP2F(sc[j][1]);
    float p2 = EXP2F(sc[j][2]);
    float p3 = EXP2F(sc[j][3]);
    int w0, w1;
    asm("v_cvt_pk_bf16_f32 %0, %1, %2" : "=v"(w0) : "v"(p0), "v"(p1));
    asm("v_cvt_pk_bf16_f32 %0, %1, %2" : "=v"(w1) : "v"(p2), "v"(p3));
    if (j < 2) { u0.i[j * 2] = w0; u0.i[j * 2 + 1] = w1; }
    else       { u1.i[(j - 2) * 2] = w0; u1.i[(j - 2) * 2 + 1] = w1; }
  }
  pa0 = u0.v;
  pa1 = u1.v;
}

// async 16B global -> LDS (dest = wave-uniform base + lane*16)
__device__ __forceinline__ void llds16(const short* g, short* l) {
  __builtin_amdgcn_global_load_lds(
      (const __attribute__((address_space(1))) unsigned int*)g,
      (__attribute__((address_space(3))) unsigned int*)l, 16, 0, 0);
}

// One launch for all three f32->bf16 casts. Ranges are exact multiples of
// 256 blocks: x = 8192, w_qkv = 3072, w_out = 1024.
__global__ __launch_bounds__(256) void cast_all(
    const float* __restrict__ x, const float* __restrict__ wq,
    const float* __restrict__ wo, short* __restrict__ xb,
    short* __restrict__ wqb, short* __restrict__ wob) {
  const int b = blockIdx.x;
  const float* src;
  short* dst;
  int idx;
  if (b < 8192)        { src = x;  dst = xb;  idx = b * 256 + threadIdx.x; }
  else if (b < 11264)  { src = wq; dst = wqb; idx = (b - 8192) * 256 + threadIdx.x; }
  else                 { src = wo; dst = wob; idx = (b - 11264) * 256 + threadIdx.x; }
  float4 f = ((const float4*)src)[idx];
  short4 o;
  o.x = f2bf(f.x); o.y = f2bf(f.y); o.z = f2bf(f.z); o.w = f2bf(f.w);
  ((short4*)dst)[idx] = o;
}

// ---------------------------------------------------------------------------
// QKV GEMM (B^T): C[m,n] = sum_k A[m,k]*Bw[n,k]. 8-phase schedule, see top.
// Buffer layout: buf b at smem + b*24576 shorts: A 16384 (256x64) | B 8192
// (128x64). Chunk c (16B): row = c>>3, stored global col-chunk = (c&7)^
// (row&7). Read of global chunk w at row: LDS chunk w^(row&7).
// ---------------------------------------------------------------------------
__global__ __launch_bounds__(512) void gemm_qkv(
    const short* __restrict__ A, const short* __restrict__ Bw,
    short* __restrict__ Qo, short* __restrict__ Ko, short* __restrict__ Vt) {
  const int K = 1024;
  __shared__ short smem[49152];  // 96 KB
  const int tid = threadIdx.x;
  const int lane = tid & 63;
  const int wave = tid >> 6;     // 0..7
  const int wr = wave >> 1;      // 0..3 (M quarter, 64 rows)
  const int wc = wave & 1;       // 0..1 (N half, 64 cols)
  const int m0 = blockIdx.y * 256;
  const int n0 = blockIdx.x * 128;
  const int mrow = lane & 15;
  const int kq = lane >> 4;

  f32x4 acc[4][4];
#pragma unroll
  for (int i = 0; i < 4; ++i)
#pragma unroll
    for (int j = 0; j < 4; ++j) acc[i][j] = (f32x4){0.f, 0.f, 0.f, 0.f};

  // stage call ca (0..3) of A-tile t into buf: 512 chunks of 16B
  auto stageA = [&](int t, int buf, int ca) {
    const int c = ca * 512 + tid;
    const int row = c >> 3;                    // 0..255
    const int sc = (c & 7) ^ (row & 7);
    llds16(A + (size_t)(m0 + row) * K + t * 64 + sc * 8,
           &smem[buf * 24576 + c * 8]);
  };
  auto stageB = [&](int t, int buf, int cb) {
    const int c = cb * 512 + tid;
    const int row = c >> 3;                    // 0..127
    const int sc = (c & 7) ^ (row & 7);
    llds16(Bw + (size_t)(n0 + row) * K + t * 64 + sc * 8,
           &smem[buf * 24576 + 16384 + c * 8]);
  };

  auto rdA = [&](const short* lA, int i, int kk) -> bf16x8 {
    const int row = wr * 64 + i * 16 + mrow;
    const int ch = (kq + 4 * kk) ^ (row & 7);
    return *(const bf16x8*)&lA[row * 64 + ch * 8];
  };
  auto rdB = [&](const short* lB, int j, int kk) -> bf16x8 {
    const int row = wc * 64 + j * 16 + mrow;
    const int ch = (kq + 4 * kk) ^ (row & 7);
    return *(const bf16x8*)&lB[row * 64 + ch * 8];
  };

  // prologue: tile 0 fully staged
  stageA(0, 0, 0); stageA(0, 0, 1); stageA(0, 0, 2); stageA(0, 0, 3);
  stageB(0, 0, 0); stageB(0, 0, 1);
  asm volatile("s_waitcnt vmcnt(0)" ::: "memory");
  __syncthreads();

#define PHASE_TAIL()                                         \
  __builtin_amdgcn_s_barrier();                              \
  asm volatile("s_waitcnt lgkmcnt(0)" ::: "memory");         \
  __builtin_amdgcn_sched_barrier(0);                         \
  __builtin_amdgcn_s_setprio(1);

#define PHASE_END()                                          \
  __builtin_amdgcn_s_setprio(0);                             \
  __builtin_amdgcn_sched_barrier(0);                         \
  __builtin_amdgcn_s_barrier();

  for (int t = 0; t < 16; ++t) {
    const int buf = t & 1;
    const int nb = buf ^ 1;
    const short* lA = &smem[buf * 24576];
    const short* lB = lA + 16384;
    bf16x8 a0, a1, a2, a3, bf0, bf1, bf2, bf3;

    // ---- phase 0: af0,af1 + all B (kk=0); issue A0,A1 of t+1 ----
    a0 = rdA(lA, 0, 0); a1 = rdA(lA, 1, 0);
    bf0 = rdB(lB, 0, 0); bf1 = rdB(lB, 1, 0);
    bf2 = rdB(lB, 2, 0); bf3 = rdB(lB, 3, 0);
    if (t < 15) { stageA(t + 1, nb, 0); stageA(t + 1, nb, 1); }
    PHASE_TAIL();
    acc[0][0] = __builtin_amdgcn_mfma_f32_16x16x32_bf16(a0, bf0, acc[0][0], 0, 0, 0);
    acc[0][1] = __builtin_amdgcn_mfma_f32_16x16x32_bf16(a0, bf1, acc[0][1], 0, 0, 0);
    acc[0][2] = __builtin_amdgcn_mfma_f32_16x16x32_bf16(a0, bf2, acc[0][2], 0, 0, 0);
    acc[0][3] = __builtin_amdgcn_mfma_f32_16x16x32_bf16(a0, bf3, acc[0][3], 0, 0, 0);
    acc[1][0] = __builtin_amdgcn_mfma_f32_16x16x32_bf16(a1, bf0, acc[1][0], 0, 0, 0);
    acc[1][1] = __builtin_amdgcn_mfma_f32_16x16x32_bf16(a1, bf1, acc[1][1], 0, 0, 0);
    acc[1][2] = __builtin_amdgcn_mfma_f32_16x16x32_bf16(a1, bf2, acc[1][2], 0, 0, 0);
    acc[1][3] = __builtin_amdgcn_mfma_f32_16x16x32_bf16(a1, bf3, acc[1][3], 0, 0, 0);
    PHASE_END();

    // ---- phase 1: af2,af3 (kk=0); issue A2,A3 ----
    a2 = rdA(lA, 2, 0); a3 = rdA(lA, 3, 0);
    if (t < 15) { stageA(t + 1, nb, 2); stageA(t + 1, nb, 3); }
    PHASE_TAIL();
    acc[2][0] = __builtin_amdgcn_mfma_f32_16x16x32_bf16(a2, bf0, acc[2][0], 0, 0, 0);
    acc[2][1] = __builtin_amdgcn_mfma_f32_16x16x32_bf16(a2, bf1, acc[2][1], 0, 0, 0);
    acc[2][2] = __builtin_amdgcn_mfma_f32_16x16x32_bf16(a2, bf2, acc[2][2], 0, 0, 0);
    acc[2][3] = __builtin_amdgcn_mfma_f32_16x16x32_bf16(a2, bf3, acc[2][3], 0, 0, 0);
    acc[3][0] = __builtin_amdgcn_mfma_f32_16x16x32_bf16(a3, bf0, acc[3][0], 0, 0, 0);
    acc[3][1] = __builtin_amdgcn_mfma_f32_16x16x32_bf16(a3, bf1, acc[3][1], 0, 0, 0);
    acc[3][2] = __builtin_amdgcn_mfma_f32_16x16x32_bf16(a3, bf2, acc[3][2], 0, 0, 0);
    acc[3][3] = __builtin_amdgcn_mfma_f32_16x16x32_bf16(a3, bf3, acc[3][3], 0, 0, 0);
    PHASE_END();

    // ---- phase 2: af0,af1 + all B (kk=1); issue B0,B1 ----
    a0 = rdA(lA, 0, 1); a1 = rdA(lA, 1, 1);
    bf0 = rdB(lB, 0, 1); bf1 = rdB(lB, 1, 1);
    bf2 = rdB(lB, 2, 1); bf3 = rdB(lB, 3, 1);
    if (t < 15) { stageB(t + 1, nb, 0); stageB(t + 1, nb, 1); }
    PHASE_TAIL();
    acc[0][0] = __builtin_amdgcn_mfma_f32_16x16x32_bf16(a0, bf0, acc[0][0], 0, 0, 0);
    acc[0][1] = __builtin_amdgcn_mfma_f32_16x16x32_bf16(a0, bf1, acc[0][1], 0, 0, 0);
    acc[0][2] = __builtin_amdgcn_mfma_f32_16x16x32_bf16(a0, bf2, acc[0][2], 0, 0, 0);
    acc[0][3] = __builtin_amdgcn_mfma_f32_16x16x32_bf16(a0, bf3, acc[0][3], 0, 0, 0);
    acc[1][0] = __builtin_amdgcn_mfma_f32_16x16x32_bf16(a1, bf0, acc[1][0], 0, 0, 0);
    acc[1][1] = __builtin_amdgcn_mfma_f32_16x16x32_bf16(a1, bf1, acc[1][1], 0, 0, 0);
    acc[1][2] = __builtin_amdgcn_mfma_f32_16x16x32_bf16(a1, bf2, acc[1][2], 0, 0, 0);
    acc[1][3] = __builtin_amdgcn_mfma_f32_16x16x32_bf16(a1, bf3, acc[1][3], 0, 0, 0);
    PHASE_END();

    // ---- phase 3: af2,af3 (kk=1); no issue ----
    a2 = rdA(lA, 2, 1); a3 = rdA(lA, 3, 1);
    PHASE_TAIL();
    acc[2][0] = __builtin_amdgcn_mfma_f32_16x16x32_bf16(a2, bf0, acc[2][0], 0, 0, 0);
    acc[2][1] = __builtin_amdgcn_mfma_f32_16x16x32_bf16(a2, bf1, acc[2][1], 0, 0, 0);
    acc[2][2] = __builtin_amdgcn_mfma_f32_16x16x32_bf16(a2, bf2, acc[2][2], 0, 0, 0);
    acc[2][3] = __builtin_amdgcn_mfma_f32_16x16x32_bf16(a2, bf3, acc[2][3], 0, 0, 0);
    acc[3][0] = __builtin_amdgcn_mfma_f32_16x16x32_bf16(a3, bf0, acc[3][0], 0, 0, 0);
    acc[3][1] = __builtin_amdgcn_mfma_f32_16x16x32_bf16(a3, bf1, acc[3][1], 0, 0, 0);
    acc[3][2] = __builtin_amdgcn_mfma_f32_16x16x32_bf16(a3, bf2, acc[3][2], 0, 0, 0);
    acc[3][3] = __builtin_amdgcn_mfma_f32_16x16x32_bf16(a3, bf3, acc[3][3], 0, 0, 0);
    __builtin_amdgcn_s_setprio(0);
    __builtin_amdgcn_sched_barrier(0);
    // tile boundary: next tile's 6 loads must be landed before any wave
    // reads buf^1 (chunks are cross-wave interleaved).
    if (t < 15) asm volatile("s_waitcnt vmcnt(0)" ::: "memory");
    __builtin_amdgcn_s_barrier();
  }
#undef PHASE_TAIL
#undef PHASE_END

  __syncthreads();   // LDS reuse for epilogue

  const int b = m0 >> 11;            // whole tile lies in one batch
  if (n0 < 2048) {
    // Q/K: row-major corner-turn (256 x stride 132 = 67.5 KB), 16B stores
    const float sc_ = ((n0 >> 10) == 1) ? SL2E : 1.0f;
    short* lC = smem;
#pragma unroll
    for (int i = 0; i < 4; ++i) {
      const int rl = wr * 64 + i * 16 + kq * 4;
#pragma unroll
      for (int j = 0; j < 4; ++j) {
        const int col = wc * 64 + j * 16 + mrow;
#pragma unroll
        for (int r = 0; r < 4; ++r)
          lC[(rl + r) * 132 + col] = f2bf(acc[i][j][r] * sc_);
      }
    }
    __syncthreads();
    short* dst = (n0 >> 10) == 0 ? Qo : Ko;
#pragma unroll
    for (int call = 0; call < 8; ++call) {
      const int cc = call * 512 + tid;
      const int row = cc >> 4;            // 0..255
      const int ch = cc & 15;
      const int t = (m0 & 2047) + row;
      const int c = (n0 + ch * 8) & 1023;
      const int h = c >> 6;
      const int d = c & 63;
      bf16x8 val = *(const bf16x8*)&lC[row * 132 + ch * 8];
      *(bf16x8*)(dst + ((size_t)(b * 16 + h) * 2048 + t) * 64 + d) = val;
    }
  } else {
    // V: transposed corner-turn (lCt[col][row], 128 x stride 264) -> Vt
    short* lCt = smem;
#pragma unroll
    for (int i = 0; i < 4; ++i) {
      const int rl = wr * 64 + i * 16 + kq * 4;
#pragma unroll
      for (int j = 0; j < 4; ++j) {
        const int col = wc * 64 + j * 16 + mrow;
#pragma unroll
        for (int r = 0; r < 4; ++r)
          lCt[col * 264 + rl + r] = f2bf(acc[i][j][r]);
      }
    }
    __syncthreads();
#pragma unroll
    for (int call = 0; call < 8; ++call) {
      const int cc = call * 512 + tid;
      const int col = cc >> 5;            // 0..127
      const int tg = cc & 31;
      const int o = n0 + col;             // 2048..3071
      const int d = o & 63;
      const int h = (o >> 6) & 15;
      const int t = (m0 & 2047) + tg * 8;
      bf16x8 val = *(const bf16x8*)&lCt[col * 264 + tg * 8];
      *(bf16x8*)(Vt + ((size_t)(b * 16 + h) * 64 + d) * 2048 + t) = val;
    }
  }
}

// Out-proj GEMM: M=8192, N=1024, BK=32, double-buffered staging, + bias, fp32.
__global__ __launch_bounds__(256) void gemm_out(
    const short* __restrict__ A, const short* __restrict__ Bw,
    const float* __restrict__ bias, float* __restrict__ Out) {
  const int K = 1024;
  __shared__ short smem[16384];
  const int tid = threadIdx.x;
  const int lane = tid & 63;
  const int wave = tid >> 6;
  const int m0 = blockIdx.y * 128;
  const int n0 = blockIdx.x * 128;
  const int wm = (wave >> 1) * 64;
  const int wn = (wave & 1) * 64;
  const int mrow = lane & 15;
  const int kq = lane >> 4;

  f32x4 acc[4][4];
#pragma unroll
  for (int i = 0; i < 4; ++i)
#pragma unroll
    for (int j = 0; j < 4; ++j) acc[i][j] = (f32x4){0.f, 0.f, 0.f, 0.f};

  auto stage = [&](int it, int buf) {
#pragma unroll
    for (int call = 0; call < 2; ++call) {
      const int cb = call * 256 + wave * 64;
      const int c = cb + lane;
      const int row = c >> 2;
      const int scol = (c & 3) ^ ((row ^ (row >> 2)) & 3);
      llds16(A + (size_t)(m0 + row) * K + it * 32 + scol * 8,
             &smem[buf * 8192 + cb * 8]);
      llds16(Bw + (size_t)(n0 + row) * K + it * 32 + scol * 8,
             &smem[buf * 8192 + 4096 + cb * 8]);
    }
  };

  stage(0, 0);
  __syncthreads();

  for (int it = 0; it < 32; ++it) {
    const int buf = it & 1;
    if (it < 31) stage(it + 1, buf ^ 1);
    const short* lA = &smem[buf * 8192];
    const short* lB = &smem[buf * 8192 + 4096];
    bf16x8 af[4], bfr[4];
#pragma unroll
    for (int i = 0; i < 4; ++i) {
      const int row = wm + i * 16 + mrow;
      af[i] = *(const bf16x8*)&lA[row * 32 + (((kq ^ row ^ (row >> 2)) & 3) * 8)];
    }
#pragma unroll
    for (int j = 0; j < 4; ++j) {
      const int row = wn + j * 16 + mrow;
      bfr[j] = *(const bf16x8*)&lB[row * 32 + (((kq ^ row ^ (row >> 2)) & 3) * 8)];
    }
#pragma unroll
    for (int i = 0; i < 4; ++i)
#pragma unroll
      for (int j = 0; j < 4; ++j)
        acc[i][j] = __builtin_amdgcn_mfma_f32_16x16x32_bf16(af[i], bfr[j], acc[i][j], 0, 0, 0);
    __syncthreads();
  }

#pragma unroll
  for (int i = 0; i < 4; ++i) {
    const int m = m0 + wm + i * 16 + kq * 4;
#pragma unroll
    for (int j = 0; j < 4; ++j) {
      const int n = n0 + wn + j * 16 + mrow;
      const float bb = bias[n];
#pragma unroll
      for (int r = 0; r < 4; ++r)
        Out[(size_t)(m + r) * 1024 + n] = acc[i][j][r] + bb;
    }
  }
}

// ---------------------------------------------------------------------------
// Flash attention R10 (unchanged). Grid (64 bh, 16). TWO q-tiles {bx,31-bx}
// per block (constant 33 seg-iterations). Swapped QK^T (mfma(K,Q)) with
// rho-permuted K rows -> softmax fully in-register, NO cross-lane ops.
// K/V fragments loaded once per kt, shared by both q-tiles. Fixed-max
// softmax (M=15 via MFMA C-init); l via ones-MFMA. Double-buffered staging,
// one barrier per kt. LDS = 32 KB -> 4 blocks/CU.
// ---------------------------------------------------------------------------
__global__ __launch_bounds__(256) void flash_attn(
    const short* __restrict__ Qg, const short* __restrict__ Kg,
    const short* __restrict__ Vtg, short* __restrict__ Og) {
  const int T = 2048;
  __shared__ short lK[2][64 * 64];
  __shared__ short lVt[2][64 * 64];
  const int tid = threadIdx.x;
  const int lane = tid & 63;
  const int wave = tid >> 6;
  const int bh = blockIdx.x;
  const int bx = blockIdx.y;         // 0..15
  const int mrow = lane & 15;
  const int kq = lane >> 4;
  const int swz = mrow & 7;
  const size_t base = (size_t)bh * T * 64;   // Q,K: [bh][t][d]
  const size_t vbase = (size_t)bh * 64 * T;  // Vt:  [bh][d][t]

  const int qt0 = bx;        // active for kt <= qt0
  const int qt1 = 31 - bx;   // active for all kt (ktmax = qt1)

  const bf16x8 ones = {0x3F80, 0x3F80, 0x3F80, 0x3F80, 0x3F80, 0x3F80, 0x3F80, 0x3F80};

  bf16x8 aq0_0, aq1_0, aq0_1, aq1_1;
  {
    const short* qp0 = Qg + base + (size_t)(qt0 * 64 + wave * 16 + mrow) * 64 + kq * 8;
    aq0_0 = *(const bf16x8*)qp0;
    aq1_0 = *(const bf16x8*)(qp0 + 32);
    const short* qp1 = Qg + base + (size_t)(qt1 * 64 + wave * 16 + mrow) * 64 + kq * 8;
    aq0_1 = *(const bf16x8*)qp1;
    aq1_1 = *(const bf16x8*)(qp1 + 32);
  }

  f32x4 acc0[4], acc1[4], lac0, lac1;
  lac0 = (f32x4){0.f, 0.f, 0.f, 0.f};
  lac1 = (f32x4){0.f, 0.f, 0.f, 0.f};
#pragma unroll
  for (int jd = 0; jd < 4; ++jd) {
    acc0[jd] = (f32x4){0.f, 0.f, 0.f, 0.f};
    acc1[jd] = (f32x4){0.f, 0.f, 0.f, 0.f};
  }

  auto stage = [&](int nt, int buf) {
#pragma unroll
    for (int call = 0; call < 2; ++call) {
      const int cb = call * 256 + wave * 64;
      const int c = cb + lane;
      const int row = c >> 3;
      const int scol = (c & 7) ^ (row & 7);
      // K row permutation rho: LDS row p holds key with bit-permuted index
      // (b5,b4,b3,b2 -> b5,b3,b2,b4) so the in-lane P pack IS the PV A-frag.
      const int grow = (row & 0x23) | ((row & 0x0C) << 1) | ((row & 0x10) >> 2);
      llds16(Kg + base + (size_t)(nt * 64 + grow) * 64 + scol * 8, &lK[buf][cb * 8]);
      llds16(Vtg + vbase + (size_t)row * T + nt * 64 + scol * 8, &lVt[buf][cb * 8]);
    }
  };

  stage(0, 0);
  __syncthreads();

  auto seg = [&](auto Aa, const short* K_, const short* Vt_, int kt) {
    constexpr bool ACT0 = decltype(Aa)::value;
    // ---- QK^T (swapped: A = K rows -> D row = K-LDS position, col = q) ----
    f32x4 sc0[4], sc1[4];
#pragma unroll
    for (int j = 0; j < 4; ++j) {
      const short* krow = &K_[(j * 16 + mrow) * 64];
      bf16x8 kb0 = *(const bf16x8*)&krow[(kq ^ swz) * 8];
      bf16x8 kb1 = *(const bf16x8*)&krow[((4 + kq) ^ swz) * 8];
      __builtin_amdgcn_s_setprio(1);
      f32x4 ss = (f32x4){-FIXED_M, -FIXED_M, -FIXED_M, -FIXED_M};
      ss = __builtin_amdgcn_mfma_f32_16x16x32_bf16(kb0, aq0_1, ss, 0, 0, 0);
      ss = __builtin_amdgcn_mfma_f32_16x16x32_bf16(kb1, aq1_1, ss, 0, 0, 0);
      sc1[j] = ss;
      if constexpr (ACT0) {
        f32x4 s2 = (f32x4){-FIXED_M, -FIXED_M, -FIXED_M, -FIXED_M};
        s2 = __builtin_amdgcn_mfma_f32_16x16x32_bf16(kb0, aq0_0, s2, 0, 0, 0);
        s2 = __builtin_amdgcn_mfma_f32_16x16x32_bf16(kb1, aq1_0, s2, 0, 0, 0);
        sc0[j] = s2;
      }
      __builtin_amdgcn_s_setprio(0);
    }

    // ---- causal masks (diagonal tiles). sc[j][r] is key
    // kt*64 + 32*(j>>1) + 8*kq + 4*(j&1) + r under rho. ----
    if (kt == qt1) {
      const int qcol = qt1 * 64 + wave * 16 + mrow;
#pragma unroll
      for (int j = 0; j < 4; ++j) {
        const int keyb = kt * 64 + ((j & 2) << 4) + (kq << 3) + ((j & 1) << 2);
#pragma unroll
        for (int r = 0; r < 4; ++r)
          if (keyb + r > qcol) sc1[j][r] = -1e30f;
      }
    }
    if constexpr (ACT0) {
      if (kt == qt0) {
        const int qcol = qt0 * 64 + wave * 16 + mrow;
#pragma unroll
        for (int j = 0; j < 4; ++j) {
          const int keyb = kt * 64 + ((j & 2) << 4) + (kq << 3) + ((j & 1) << 2);
#pragma unroll
          for (int r = 0; r < 4; ++r)
            if (keyb + r > qcol) sc0[j][r] = -1e30f;
        }
      }
    }

    // ---- softmax: exp2 + direct in-lane pack (no shuffles) ----
    bf16x8 pa0_1, pa1_1, pa0_0, pa1_0;
    softmax_pack(sc1, pa0_1, pa1_1);
    lac1 = __builtin_amdgcn_mfma_f32_16x16x32_bf16(pa0_1, ones, lac1, 0, 0, 0);
    lac1 = __builtin_amdgcn_mfma_f32_16x16x32_bf16(pa1_1, ones, lac1, 0, 0, 0);
    if constexpr (ACT0) {
      softmax_pack(sc0, pa0_0, pa1_0);
      lac0 = __builtin_amdgcn_mfma_f32_16x16x32_bf16(pa0_0, ones, lac0, 0, 0, 0);
      lac0 = __builtin_amdgcn_mfma_f32_16x16x32_bf16(pa1_0, ones, lac0, 0, 0, 0);
    }

    // ---- PV: V fragments loaded once, shared by both q-tiles ----
#pragma unroll
    for (int jd = 0; jd < 4; ++jd) {
      const short* vrow = &Vt_[(jd * 16 + mrow) * 64];
      bf16x8 vb0 = *(const bf16x8*)&vrow[(kq ^ swz) * 8];
      bf16x8 vb1 = *(const bf16x8*)&vrow[((4 + kq) ^ swz) * 8];
      __builtin_amdgcn_s_setprio(1);
      acc1[jd] = __builtin_amdgcn_mfma_f32_16x16x32_bf16(pa0_1, vb0, acc1[jd], 0, 0, 0);
      acc1[jd] = __builtin_amdgcn_mfma_f32_16x16x32_bf16(pa1_1, vb1, acc1[jd], 0, 0, 0);
      if constexpr (ACT0) {
        acc0[jd] = __builtin_amdgcn_mfma_f32_16x16x32_bf16(pa0_0, vb0, acc0[jd], 0, 0, 0);
        acc0[jd] = __builtin_amdgcn_mfma_f32_16x16x32_bf16(pa1_0, vb1, acc0[jd], 0, 0, 0);
      }
      __builtin_amdgcn_s_setprio(0);
    }
  };

  for (int kt = 0; kt <= qt1; ++kt) {
    const int bcur = kt & 1;
    if (kt < qt1) stage(kt + 1, bcur ^ 1);
    if (kt <= qt0) seg(BoolC<true>{}, lK[bcur], lVt[bcur], kt);
    else           seg(BoolC<false>{}, lK[bcur], lVt[bcur], kt);
    __syncthreads();
  }

  const int b = bh >> 4;
  const int h = bh & 15;
#pragma unroll
  for (int r = 0; r < 4; ++r) {
    const float inv0 = 1.0f / lac0[r];
    const int t0 = qt0 * 64 + wave * 16 + kq * 4 + r;
#pragma unroll
    for (int jd = 0; jd < 4; ++jd) {
      const int col = h * 64 + jd * 16 + mrow;
      Og[((size_t)b * 2048 + t0) * 1024 + col] = f2bf(acc0[jd][r] * inv0);
    }
    const float inv1 = 1.0f / lac1[r];
    const int t1 = qt1 * 64 + wave * 16 + kq * 4 + r;
#pragma unroll
    for (int jd = 0; jd < 4; ++jd) {
      const int col = h * 64 + jd * 16 + mrow;
      Og[((size_t)b * 2048 + t1) * 1024 + col] = f2bf(acc1[jd][r] * inv1);
    }
  }
}

extern "C" void kernel_launch(void* const* d_in, const int* in_sizes, int n_in,
                              void* d_out, int out_size, void* d_ws, size_t ws_size,
                              hipStream_t stream) {
  const float* x = (const float*)d_in[0];
  const float* w_qkv = (const float*)d_in[1];
  const float* w_out = (const float*)d_in[2];
  const float* b_out = (const float*)d_in[3];
  float* out = (float*)d_out;

  char* ws = (char*)d_ws;
  const size_t NX = 8192ull * 1024;
  const size_t NWQ = 3072ull * 1024;
  const size_t NWO = 1024ull * 1024;
  const size_t NQ = 64ull * 2048 * 64;
  size_t off = 0;
  short* xb    = (short*)(ws + off); off += NX * 2;
  short* wqkvb = (short*)(ws + off); off += NWQ * 2;
  short* woutb = (short*)(ws + off); off += NWO * 2;
  short* q     = (short*)(ws + off); off += NQ * 2;
  short* k     = (short*)(ws + off); off += NQ * 2;
  short* vt    = (short*)(ws + off); off += NQ * 2;  // V stored transposed [bh][d][t]
  short* attb  = (short*)(ws + off); off += NX * 2;
  if (off > ws_size) return;

  cast_all<<<12288, 256, 0, stream>>>(x, w_qkv, w_out, xb, wqkvb, woutb);
  gemm_qkv<<<dim3(24, 32), 512, 0, stream>>>(xb, wqkvb, q, k, vt);
  flash_attn<<<dim3(64, 16), 256, 0, stream>>>(q, k, vt, attb);
  gemm_out<<<dim3(8, 64), 256, 0, stream>>>(attb, woutb, b_out, out);
}

// Round 6
// 248.158 us; speedup vs baseline: 1.0592x; 1.0013x over previous
//
#include <hip/hip_runtime.h>
#include <stdint.h>

// MultiHeadAttention: B=4, T=2048, C=1024, H=16, D=64, causal, scale=1/8.
// R14: flash_attn -> FOUR q-tiles/block {bx,31-bx,15-bx,16+bx}, grid (64,8)
// (constant 66 seg-tiles/block; one K/V stream amortized 2x vs R10), tiles
// processed in PAIRS sharing K/V fragment reads, R10's rho-relabeled
// in-register softmax kept, counted vmcnt(4) + dual raw s_barrier (no full
// drain in loop). gemm_qkv = R13 8-phase counted-vmcnt; gemm_out/cast_all
// unchanged.
//
// MFMA 16x16x32 bf16 layouts:
//   A frag: m = lane&15, k = (lane>>4)*8 + j
//   B frag: n = lane&15, k = (lane>>4)*8 + j
//   C/D:    col = lane&15, row = (lane>>4)*4 + reg

typedef __attribute__((ext_vector_type(8))) short bf16x8;
typedef __attribute__((ext_vector_type(4))) float f32x4;

#define EXP2F(x) __builtin_amdgcn_exp2f(x)
#define SL2E 0.18033688011112042f  /* 0.125 * log2(e) */
#define FIXED_M 15.0f

template <bool B> struct BoolC { static constexpr bool value = B; };
template <int I> struct IntC { static constexpr int value = I; };

__device__ __forceinline__ short f2bf(float f) {
  union { float f; unsigned u; } c; c.f = f;
  unsigned u = c.u;
  unsigned r = (u + 0x7fffu + ((u >> 16) & 1u)) >> 16;
  return (short)(unsigned short)r;
}

// sc[j][r] = S at LDS K position 16j + 4kq + r, q = mrow (log2 units).
// Direct in-lane pack -> PV A-fragments (rho relabeling, see flash_attn).
__device__ __forceinline__ void softmax_pack(const f32x4* sc, bf16x8& pa0, bf16x8& pa1) {
  union U { int i[4]; bf16x8 v; };
  U u0, u1;
#pragma unroll
  for (int j = 0; j < 4; ++j) {
    float p0 = EXP2F(sc[j][0]);
    float p1 = EXP2F(sc[j][1]);
    float p2 = EXP2F(sc[j][2]);
    float p3 = EXP2F(sc[j][3]);
    int w0, w1;
    asm("v_cvt_pk_bf16_f32 %0, %1, %2" : "=v"(w0) : "v"(p0), "v"(p1));
    asm("v_cvt_pk_bf16_f32 %0, %1, %2" : "=v"(w1) : "v"(p2), "v"(p3));
    if (j < 2) { u0.i[j * 2] = w0; u0.i[j * 2 + 1] = w1; }
    else       { u1.i[(j - 2) * 2] = w0; u1.i[(j - 2) * 2 + 1] = w1; }
  }
  pa0 = u0.v;
  pa1 = u1.v;
}

// async 16B global -> LDS (dest = wave-uniform base + lane*16)
__device__ __forceinline__ void llds16(const short* g, short* l) {
  __builtin_amdgcn_global_load_lds(
      (const __attribute__((address_space(1))) unsigned int*)g,
      (__attribute__((address_space(3))) unsigned int*)l, 16, 0, 0);
}

// One launch for all three f32->bf16 casts. Ranges are exact multiples of
// 256 blocks: x = 8192, w_qkv = 3072, w_out = 1024.
__global__ __launch_bounds__(256) void cast_all(
    const float* __restrict__ x, const float* __restrict__ wq,
    const float* __restrict__ wo, short* __restrict__ xb,
    short* __restrict__ wqb, short* __restrict__ wob) {
  const int b = blockIdx.x;
  const float* src;
  short* dst;
  int idx;
  if (b < 8192)        { src = x;  dst = xb;  idx = b * 256 + threadIdx.x; }
  else if (b < 11264)  { src = wq; dst = wqb; idx = (b - 8192) * 256 + threadIdx.x; }
  else                 { src = wo; dst = wob; idx = (b - 11264) * 256 + threadIdx.x; }
  float4 f = ((const float4*)src)[idx];
  short4 o;
  o.x = f2bf(f.x); o.y = f2bf(f.y); o.z = f2bf(f.z); o.w = f2bf(f.w);
  ((short4*)dst)[idx] = o;
}

// ---------------------------------------------------------------------------
// QKV GEMM (B^T): 8-phase counted-vmcnt schedule (R13). BM=256 BN=128 BK=64,
// 512 thr (8 waves, 4Mx2N), LDS 96KB double-buffered. vmcnt(0) only at tile
// boundary; staging swizzle (c&7)^(row&7) on global source + same XOR on
// reads. Epilogue corner-turn.
// ---------------------------------------------------------------------------
__global__ __launch_bounds__(512) void gemm_qkv(
    const short* __restrict__ A, const short* __restrict__ Bw,
    short* __restrict__ Qo, short* __restrict__ Ko, short* __restrict__ Vt) {
  const int K = 1024;
  __shared__ short smem[49152];  // 96 KB
  const int tid = threadIdx.x;
  const int lane = tid & 63;
  const int wave = tid >> 6;     // 0..7
  const int wr = wave >> 1;      // 0..3 (M quarter, 64 rows)
  const int wc = wave & 1;       // 0..1 (N half, 64 cols)
  const int m0 = blockIdx.y * 256;
  const int n0 = blockIdx.x * 128;
  const int mrow = lane & 15;
  const int kq = lane >> 4;

  f32x4 acc[4][4];
#pragma unroll
  for (int i = 0; i < 4; ++i)
#pragma unroll
    for (int j = 0; j < 4; ++j) acc[i][j] = (f32x4){0.f, 0.f, 0.f, 0.f};

  auto stageA = [&](int t, int buf, int ca) {
    const int c = ca * 512 + tid;
    const int row = c >> 3;                    // 0..255
    const int sc = (c & 7) ^ (row & 7);
    llds16(A + (size_t)(m0 + row) * K + t * 64 + sc * 8,
           &smem[buf * 24576 + c * 8]);
  };
  auto stageB = [&](int t, int buf, int cb) {
    const int c = cb * 512 + tid;
    const int row = c >> 3;                    // 0..127
    const int sc = (c & 7) ^ (row & 7);
    llds16(Bw + (size_t)(n0 + row) * K + t * 64 + sc * 8,
           &smem[buf * 24576 + 16384 + c * 8]);
  };

  auto rdA = [&](const short* lA, int i, int kk) -> bf16x8 {
    const int row = wr * 64 + i * 16 + mrow;
    const int ch = (kq + 4 * kk) ^ (row & 7);
    return *(const bf16x8*)&lA[row * 64 + ch * 8];
  };
  auto rdB = [&](const short* lB, int j, int kk) -> bf16x8 {
    const int row = wc * 64 + j * 16 + mrow;
    const int ch = (kq + 4 * kk) ^ (row & 7);
    return *(const bf16x8*)&lB[row * 64 + ch * 8];
  };

  stageA(0, 0, 0); stageA(0, 0, 1); stageA(0, 0, 2); stageA(0, 0, 3);
  stageB(0, 0, 0); stageB(0, 0, 1);
  asm volatile("s_waitcnt vmcnt(0)" ::: "memory");
  __syncthreads();

#define PHASE_TAIL()                                         \
  __builtin_amdgcn_s_barrier();                              \
  asm volatile("s_waitcnt lgkmcnt(0)" ::: "memory");         \
  __builtin_amdgcn_sched_barrier(0);                         \
  __builtin_amdgcn_s_setprio(1);

#define PHASE_END()                                          \
  __builtin_amdgcn_s_setprio(0);                             \
  __builtin_amdgcn_sched_barrier(0);                         \
  __builtin_amdgcn_s_barrier();

  for (int t = 0; t < 16; ++t) {
    const int buf = t & 1;
    const int nb = buf ^ 1;
    const short* lA = &smem[buf * 24576];
    const short* lB = lA + 16384;
    bf16x8 a0, a1, a2, a3, bf0, bf1, bf2, bf3;

    a0 = rdA(lA, 0, 0); a1 = rdA(lA, 1, 0);
    bf0 = rdB(lB, 0, 0); bf1 = rdB(lB, 1, 0);
    bf2 = rdB(lB, 2, 0); bf3 = rdB(lB, 3, 0);
    if (t < 15) { stageA(t + 1, nb, 0); stageA(t + 1, nb, 1); }
    PHASE_TAIL();
    acc[0][0] = __builtin_amdgcn_mfma_f32_16x16x32_bf16(a0, bf0, acc[0][0], 0, 0, 0);
    acc[0][1] = __builtin_amdgcn_mfma_f32_16x16x32_bf16(a0, bf1, acc[0][1], 0, 0, 0);
    acc[0][2] = __builtin_amdgcn_mfma_f32_16x16x32_bf16(a0, bf2, acc[0][2], 0, 0, 0);
    acc[0][3] = __builtin_amdgcn_mfma_f32_16x16x32_bf16(a0, bf3, acc[0][3], 0, 0, 0);
    acc[1][0] = __builtin_amdgcn_mfma_f32_16x16x32_bf16(a1, bf0, acc[1][0], 0, 0, 0);
    acc[1][1] = __builtin_amdgcn_mfma_f32_16x16x32_bf16(a1, bf1, acc[1][1], 0, 0, 0);
    acc[1][2] = __builtin_amdgcn_mfma_f32_16x16x32_bf16(a1, bf2, acc[1][2], 0, 0, 0);
    acc[1][3] = __builtin_amdgcn_mfma_f32_16x16x32_bf16(a1, bf3, acc[1][3], 0, 0, 0);
    PHASE_END();

    a2 = rdA(lA, 2, 0); a3 = rdA(lA, 3, 0);
    if (t < 15) { stageA(t + 1, nb, 2); stageA(t + 1, nb, 3); }
    PHASE_TAIL();
    acc[2][0] = __builtin_amdgcn_mfma_f32_16x16x32_bf16(a2, bf0, acc[2][0], 0, 0, 0);
    acc[2][1] = __builtin_amdgcn_mfma_f32_16x16x32_bf16(a2, bf1, acc[2][1], 0, 0, 0);
    acc[2][2] = __builtin_amdgcn_mfma_f32_16x16x32_bf16(a2, bf2, acc[2][2], 0, 0, 0);
    acc[2][3] = __builtin_amdgcn_mfma_f32_16x16x32_bf16(a2, bf3, acc[2][3], 0, 0, 0);
    acc[3][0] = __builtin_amdgcn_mfma_f32_16x16x32_bf16(a3, bf0, acc[3][0], 0, 0, 0);
    acc[3][1] = __builtin_amdgcn_mfma_f32_16x16x32_bf16(a3, bf1, acc[3][1], 0, 0, 0);
    acc[3][2] = __builtin_amdgcn_mfma_f32_16x16x32_bf16(a3, bf2, acc[3][2], 0, 0, 0);
    acc[3][3] = __builtin_amdgcn_mfma_f32_16x16x32_bf16(a3, bf3, acc[3][3], 0, 0, 0);
    PHASE_END();

    a0 = rdA(lA, 0, 1); a1 = rdA(lA, 1, 1);
    bf0 = rdB(lB, 0, 1); bf1 = rdB(lB, 1, 1);
    bf2 = rdB(lB, 2, 1); bf3 = rdB(lB, 3, 1);
    if (t < 15) { stageB(t + 1, nb, 0); stageB(t + 1, nb, 1); }
    PHASE_TAIL();
    acc[0][0] = __builtin_amdgcn_mfma_f32_16x16x32_bf16(a0, bf0, acc[0][0], 0, 0, 0);
    acc[0][1] = __builtin_amdgcn_mfma_f32_16x16x32_bf16(a0, bf1, acc[0][1], 0, 0, 0);
    acc[0][2] = __builtin_amdgcn_mfma_f32_16x16x32_bf16(a0, bf2, acc[0][2], 0, 0, 0);
    acc[0][3] = __builtin_amdgcn_mfma_f32_16x16x32_bf16(a0, bf3, acc[0][3], 0, 0, 0);
    acc[1][0] = __builtin_amdgcn_mfma_f32_16x16x32_bf16(a1, bf0, acc[1][0], 0, 0, 0);
    acc[1][1] = __builtin_amdgcn_mfma_f32_16x16x32_bf16(a1, bf1, acc[1][1], 0, 0, 0);
    acc[1][2] = __builtin_amdgcn_mfma_f32_16x16x32_bf16(a1, bf2, acc[1][2], 0, 0, 0);
    acc[1][3] = __builtin_amdgcn_mfma_f32_16x16x32_bf16(a1, bf3, acc[1][3], 0, 0, 0);
    PHASE_END();

    a2 = rdA(lA, 2, 1); a3 = rdA(lA, 3, 1);
    PHASE_TAIL();
    acc[2][0] = __builtin_amdgcn_mfma_f32_16x16x32_bf16(a2, bf0, acc[2][0], 0, 0, 0);
    acc[2][1] = __builtin_amdgcn_mfma_f32_16x16x32_bf16(a2, bf1, acc[2][1], 0, 0, 0);
    acc[2][2] = __builtin_amdgcn_mfma_f32_16x16x32_bf16(a2, bf2, acc[2][2], 0, 0, 0);
    acc[2][3] = __builtin_amdgcn_mfma_f32_16x16x32_bf16(a2, bf3, acc[2][3], 0, 0, 0);
    acc[3][0] = __builtin_amdgcn_mfma_f32_16x16x32_bf16(a3, bf0, acc[3][0], 0, 0, 0);
    acc[3][1] = __builtin_amdgcn_mfma_f32_16x16x32_bf16(a3, bf1, acc[3][1], 0, 0, 0);
    acc[3][2] = __builtin_amdgcn_mfma_f32_16x16x32_bf16(a3, bf2, acc[3][2], 0, 0, 0);
    acc[3][3] = __builtin_amdgcn_mfma_f32_16x16x32_bf16(a3, bf3, acc[3][3], 0, 0, 0);
    __builtin_amdgcn_s_setprio(0);
    __builtin_amdgcn_sched_barrier(0);
    if (t < 15) asm volatile("s_waitcnt vmcnt(0)" ::: "memory");
    __builtin_amdgcn_s_barrier();
  }
#undef PHASE_TAIL
#undef PHASE_END

  __syncthreads();   // LDS reuse for epilogue

  const int b = m0 >> 11;            // whole tile lies in one batch
  if (n0 < 2048) {
    const float sc_ = ((n0 >> 10) == 1) ? SL2E : 1.0f;
    short* lC = smem;
#pragma unroll
    for (int i = 0; i < 4; ++i) {
      const int rl = wr * 64 + i * 16 + kq * 4;
#pragma unroll
      for (int j = 0; j < 4; ++j) {
        const int col = wc * 64 + j * 16 + mrow;
#pragma unroll
        for (int r = 0; r < 4; ++r)
          lC[(rl + r) * 132 + col] = f2bf(acc[i][j][r] * sc_);
      }
    }
    __syncthreads();
    short* dst = (n0 >> 10) == 0 ? Qo : Ko;
#pragma unroll
    for (int call = 0; call < 8; ++call) {
      const int cc = call * 512 + tid;
      const int row = cc >> 4;            // 0..255
      const int ch = cc & 15;
      const int t = (m0 & 2047) + row;
      const int c = (n0 + ch * 8) & 1023;
      const int h = c >> 6;
      const int d = c & 63;
      bf16x8 val = *(const bf16x8*)&lC[row * 132 + ch * 8];
      *(bf16x8*)(dst + ((size_t)(b * 16 + h) * 2048 + t) * 64 + d) = val;
    }
  } else {
    short* lCt = smem;
#pragma unroll
    for (int i = 0; i < 4; ++i) {
      const int rl = wr * 64 + i * 16 + kq * 4;
#pragma unroll
      for (int j = 0; j < 4; ++j) {
        const int col = wc * 64 + j * 16 + mrow;
#pragma unroll
        for (int r = 0; r < 4; ++r)
          lCt[col * 264 + rl + r] = f2bf(acc[i][j][r]);
      }
    }
    __syncthreads();
#pragma unroll
    for (int call = 0; call < 8; ++call) {
      const int cc = call * 512 + tid;
      const int col = cc >> 5;            // 0..127
      const int tg = cc & 31;
      const int o = n0 + col;             // 2048..3071
      const int d = o & 63;
      const int h = (o >> 6) & 15;
      const int t = (m0 & 2047) + tg * 8;
      bf16x8 val = *(const bf16x8*)&lCt[col * 264 + tg * 8];
      *(bf16x8*)(Vt + ((size_t)(b * 16 + h) * 64 + d) * 2048 + t) = val;
    }
  }
}

// Out-proj GEMM: M=8192, N=1024, BK=32, double-buffered staging, + bias, fp32.
__global__ __launch_bounds__(256) void gemm_out(
    const short* __restrict__ A, const short* __restrict__ Bw,
    const float* __restrict__ bias, float* __restrict__ Out) {
  const int K = 1024;
  __shared__ short smem[16384];
  const int tid = threadIdx.x;
  const int lane = tid & 63;
  const int wave = tid >> 6;
  const int m0 = blockIdx.y * 128;
  const int n0 = blockIdx.x * 128;
  const int wm = (wave >> 1) * 64;
  const int wn = (wave & 1) * 64;
  const int mrow = lane & 15;
  const int kq = lane >> 4;

  f32x4 acc[4][4];
#pragma unroll
  for (int i = 0; i < 4; ++i)
#pragma unroll
    for (int j = 0; j < 4; ++j) acc[i][j] = (f32x4){0.f, 0.f, 0.f, 0.f};

  auto stage = [&](int it, int buf) {
#pragma unroll
    for (int call = 0; call < 2; ++call) {
      const int cb = call * 256 + wave * 64;
      const int c = cb + lane;
      const int row = c >> 2;
      const int scol = (c & 3) ^ ((row ^ (row >> 2)) & 3);
      llds16(A + (size_t)(m0 + row) * K + it * 32 + scol * 8,
             &smem[buf * 8192 + cb * 8]);
      llds16(Bw + (size_t)(n0 + row) * K + it * 32 + scol * 8,
             &smem[buf * 8192 + 4096 + cb * 8]);
    }
  };

  stage(0, 0);
  __syncthreads();

  for (int it = 0; it < 32; ++it) {
    const int buf = it & 1;
    if (it < 31) stage(it + 1, buf ^ 1);
    const short* lA = &smem[buf * 8192];
    const short* lB = &smem[buf * 8192 + 4096];
    bf16x8 af[4], bfr[4];
#pragma unroll
    for (int i = 0; i < 4; ++i) {
      const int row = wm + i * 16 + mrow;
      af[i] = *(const bf16x8*)&lA[row * 32 + (((kq ^ row ^ (row >> 2)) & 3) * 8)];
    }
#pragma unroll
    for (int j = 0; j < 4; ++j) {
      const int row = wn + j * 16 + mrow;
      bfr[j] = *(const bf16x8*)&lB[row * 32 + (((kq ^ row ^ (row >> 2)) & 3) * 8)];
    }
#pragma unroll
    for (int i = 0; i < 4; ++i)
#pragma unroll
      for (int j = 0; j < 4; ++j)
        acc[i][j] = __builtin_amdgcn_mfma_f32_16x16x32_bf16(af[i], bfr[j], acc[i][j], 0, 0, 0);
    __syncthreads();
  }

#pragma unroll
  for (int i = 0; i < 4; ++i) {
    const int m = m0 + wm + i * 16 + kq * 4;
#pragma unroll
    for (int j = 0; j < 4; ++j) {
      const int n = n0 + wn + j * 16 + mrow;
      const float bb = bias[n];
#pragma unroll
      for (int r = 0; r < 4; ++r)
        Out[(size_t)(m + r) * 1024 + n] = acc[i][j][r] + bb;
    }
  }
}

// ---------------------------------------------------------------------------
// Flash attention R14. Grid (64 bh, 8). Block = 4 waves, FOUR q-tiles
// {bx, 31-bx, 15-bx, 16+bx} (constant 66 seg-tiles/block), one K/Vt stream
// kt = 0..31-bx. Tiles processed in pairs (0,1) and (2,3) sharing K/V
// fragment reads. Swapped QK^T (mfma(K,Q)) with rho-permuted K rows ->
// softmax fully in-register, NO cross-lane ops. Fixed-max softmax (M=15
// via MFMA C-init); l via ones-MFMA. Double-buffered staging with counted
// vmcnt(4) + dual raw s_barrier (no full drain in loop). LDS = 32 KB.
// ---------------------------------------------------------------------------
__global__ __launch_bounds__(256) void flash_attn(
    const short* __restrict__ Qg, const short* __restrict__ Kg,
    const short* __restrict__ Vtg, short* __restrict__ Og) {
  const int T = 2048;
  __shared__ short lK[2][64 * 64];
  __shared__ short lVt[2][64 * 64];
  const int tid = threadIdx.x;
  const int lane = tid & 63;
  const int wave = tid >> 6;
  const int bh = blockIdx.x;
  const int bx = blockIdx.y;         // 0..7
  const int mrow = lane & 15;
  const int kq = lane >> 4;
  const int swz = mrow & 7;
  const size_t base = (size_t)bh * T * 64;   // Q,K: [bh][t][d]
  const size_t vbase = (size_t)bh * 64 * T;  // Vt:  [bh][d][t]

  int qts[4];
  qts[0] = bx;         // pair 0: active kt <= bx
  qts[1] = 31 - bx;    // pair 0 anchor: active all kt (ktmax)
  qts[2] = 15 - bx;    // pair 1: active kt <= 15-bx
  qts[3] = 16 + bx;    // pair 1 anchor: active kt <= 16+bx

  const bf16x8 ones = {0x3F80, 0x3F80, 0x3F80, 0x3F80, 0x3F80, 0x3F80, 0x3F80, 0x3F80};

  bf16x8 aq0[4], aq1[4];
#pragma unroll
  for (int s = 0; s < 4; ++s) {
    const short* qp = Qg + base + (size_t)(qts[s] * 64 + wave * 16 + mrow) * 64 + kq * 8;
    aq0[s] = *(const bf16x8*)qp;
    aq1[s] = *(const bf16x8*)(qp + 32);
  }

  f32x4 acc[4][4], lac[4];
#pragma unroll
  for (int s = 0; s < 4; ++s) {
    lac[s] = (f32x4){0.f, 0.f, 0.f, 0.f};
#pragma unroll
    for (int jd = 0; jd < 4; ++jd) acc[s][jd] = (f32x4){0.f, 0.f, 0.f, 0.f};
  }

  auto stage = [&](int nt, int buf) {
#pragma unroll
    for (int call = 0; call < 2; ++call) {
      const int cb = call * 256 + wave * 64;
      const int c = cb + lane;
      const int row = c >> 3;
      const int scol = (c & 7) ^ (row & 7);
      // K row permutation rho: LDS row p holds key with bit-permuted index
      // (b5,b4,b3,b2 -> b5,b3,b2,b4) so the in-lane P pack IS the PV A-frag.
      const int grow = (row & 0x23) | ((row & 0x0C) << 1) | ((row & 0x10) >> 2);
      llds16(Kg + base + (size_t)(nt * 64 + grow) * 64 + scol * 8, &lK[buf][cb * 8]);
      llds16(Vtg + vbase + (size_t)row * T + nt * 64 + scol * 8, &lVt[buf][cb * 8]);
    }
  };

  // seg for tile pair (PI, PI+1): anchor tile PI+1 assumed active; tile PI
  // active iff ACT0. K/V fragments read once, shared by both tiles.
  auto seg = [&](auto Aa, auto Pi, const short* K_, const short* Vt_, int kt) {
    constexpr bool ACT0 = decltype(Aa)::value;
    constexpr int pi = decltype(Pi)::value;
    f32x4 sc0[4], sc1[4];
#pragma unroll
    for (int j = 0; j < 4; ++j) {
      const short* krow = &K_[(j * 16 + mrow) * 64];
      bf16x8 kb0 = *(const bf16x8*)&krow[(kq ^ swz) * 8];
      bf16x8 kb1 = *(const bf16x8*)&krow[((4 + kq) ^ swz) * 8];
      __builtin_amdgcn_s_setprio(1);
      f32x4 ss = (f32x4){-FIXED_M, -FIXED_M, -FIXED_M, -FIXED_M};
      ss = __builtin_amdgcn_mfma_f32_16x16x32_bf16(kb0, aq0[pi + 1], ss, 0, 0, 0);
      ss = __builtin_amdgcn_mfma_f32_16x16x32_bf16(kb1, aq1[pi + 1], ss, 0, 0, 0);
      sc1[j] = ss;
      if constexpr (ACT0) {
        f32x4 s2 = (f32x4){-FIXED_M, -FIXED_M, -FIXED_M, -FIXED_M};
        s2 = __builtin_amdgcn_mfma_f32_16x16x32_bf16(kb0, aq0[pi], s2, 0, 0, 0);
        s2 = __builtin_amdgcn_mfma_f32_16x16x32_bf16(kb1, aq1[pi], s2, 0, 0, 0);
        sc0[j] = s2;
      }
      __builtin_amdgcn_s_setprio(0);
    }

    // causal masks (diagonal tiles). sc[j][r] is key
    // kt*64 + 32*(j>>1) + 8*kq + 4*(j&1) + r under rho.
    if (kt == qts[pi + 1]) {
      const int qcol = qts[pi + 1] * 64 + wave * 16 + mrow;
#pragma unroll
      for (int j = 0; j < 4; ++j) {
        const int keyb = kt * 64 + ((j & 2) << 4) + (kq << 3) + ((j & 1) << 2);
#pragma unroll
        for (int r = 0; r < 4; ++r)
          if (keyb + r > qcol) sc1[j][r] = -1e30f;
      }
    }
    if constexpr (ACT0) {
      if (kt == qts[pi]) {
        const int qcol = qts[pi] * 64 + wave * 16 + mrow;
#pragma unroll
        for (int j = 0; j < 4; ++j) {
          const int keyb = kt * 64 + ((j & 2) << 4) + (kq << 3) + ((j & 1) << 2);
#pragma unroll
          for (int r = 0; r < 4; ++r)
            if (keyb + r > qcol) sc0[j][r] = -1e30f;
        }
      }
    }

    bf16x8 pa0_1, pa1_1, pa0_0, pa1_0;
    softmax_pack(sc1, pa0_1, pa1_1);
    lac[pi + 1] = __builtin_amdgcn_mfma_f32_16x16x32_bf16(pa0_1, ones, lac[pi + 1], 0, 0, 0);
    lac[pi + 1] = __builtin_amdgcn_mfma_f32_16x16x32_bf16(pa1_1, ones, lac[pi + 1], 0, 0, 0);
    if constexpr (ACT0) {
      softmax_pack(sc0, pa0_0, pa1_0);
      lac[pi] = __builtin_amdgcn_mfma_f32_16x16x32_bf16(pa0_0, ones, lac[pi], 0, 0, 0);
      lac[pi] = __builtin_amdgcn_mfma_f32_16x16x32_bf16(pa1_0, ones, lac[pi], 0, 0, 0);
    }

#pragma unroll
    for (int jd = 0; jd < 4; ++jd) {
      const short* vrow = &Vt_[(jd * 16 + mrow) * 64];
      bf16x8 vb0 = *(const bf16x8*)&vrow[(kq ^ swz) * 8];
      bf16x8 vb1 = *(const bf16x8*)&vrow[((4 + kq) ^ swz) * 8];
      __builtin_amdgcn_s_setprio(1);
      acc[pi + 1][jd] = __builtin_amdgcn_mfma_f32_16x16x32_bf16(pa0_1, vb0, acc[pi + 1][jd], 0, 0, 0);
      acc[pi + 1][jd] = __builtin_amdgcn_mfma_f32_16x16x32_bf16(pa1_1, vb1, acc[pi + 1][jd], 0, 0, 0);
      if constexpr (ACT0) {
        acc[pi][jd] = __builtin_amdgcn_mfma_f32_16x16x32_bf16(pa0_0, vb0, acc[pi][jd], 0, 0, 0);
        acc[pi][jd] = __builtin_amdgcn_mfma_f32_16x16x32_bf16(pa1_0, vb1, acc[pi][jd], 0, 0, 0);
      }
      __builtin_amdgcn_s_setprio(0);
    }
  };

  stage(0, 0);
  const int ktmax = qts[1];
  for (int kt = 0; kt <= ktmax; ++kt) {
    const int bcur = kt & 1;
    if (kt < ktmax) {
      stage(kt + 1, bcur ^ 1);
      asm volatile("s_waitcnt vmcnt(4)" ::: "memory");  // kt's 4 landed
    } else {
      asm volatile("s_waitcnt vmcnt(0)" ::: "memory");
    }
    __builtin_amdgcn_s_barrier();   // all waves' kt loads landed
    const short* K_ = lK[bcur];
    const short* Vt_ = lVt[bcur];
    // pair 0: anchor qts[1] active for all kt
    if (kt <= qts[0]) seg(BoolC<true>{}, IntC<0>{}, K_, Vt_, kt);
    else              seg(BoolC<false>{}, IntC<0>{}, K_, Vt_, kt);
    // pair 1: anchor qts[3] active while kt <= 16+bx
    if (kt <= qts[3]) {
      if (kt <= qts[2]) seg(BoolC<true>{}, IntC<1 * 2>{}, K_, Vt_, kt);
      else              seg(BoolC<false>{}, IntC<1 * 2>{}, K_, Vt_, kt);
    }
    __builtin_amdgcn_s_barrier();   // buf[bcur] free for restage next iter
  }

  const int b = bh >> 4;
  const int h = bh & 15;
#pragma unroll
  for (int s = 0; s < 4; ++s) {
#pragma unroll
    for (int r = 0; r < 4; ++r) {
      const float inv = 1.0f / lac[s][r];
      const int t = qts[s] * 64 + wave * 16 + kq * 4 + r;
#pragma unroll
      for (int jd = 0; jd < 4; ++jd) {
        const int col = h * 64 + jd * 16 + mrow;
        Og[((size_t)b * 2048 + t) * 1024 + col] = f2bf(acc[s][jd][r] * inv);
      }
    }
  }
}

extern "C" void kernel_launch(void* const* d_in, const int* in_sizes, int n_in,
                              void* d_out, int out_size, void* d_ws, size_t ws_size,
                              hipStream_t stream) {
  const float* x = (const float*)d_in[0];
  const float* w_qkv = (const float*)d_in[1];
  const float* w_out = (const float*)d_in[2];
  const float* b_out = (const float*)d_in[3];
  float* out = (float*)d_out;

  char* ws = (char*)d_ws;
  const size_t NX = 8192ull * 1024;
  const size_t NWQ = 3072ull * 1024;
  const size_t NWO = 1024ull * 1024;
  const size_t NQ = 64ull * 2048 * 64;
  size_t off = 0;
  short* xb    = (short*)(ws + off); off += NX * 2;
  short* wqkvb = (short*)(ws + off); off += NWQ * 2;
  short* woutb = (short*)(ws + off); off += NWO * 2;
  short* q     = (short*)(ws + off); off += NQ * 2;
  short* k     = (short*)(ws + off); off += NQ * 2;
  short* vt    = (short*)(ws + off); off += NQ * 2;  // V stored transposed [bh][d][t]
  short* attb  = (short*)(ws + off); off += NX * 2;
  if (off > ws_size) return;

  cast_all<<<12288, 256, 0, stream>>>(x, w_qkv, w_out, xb, wqkvb, woutb);
  gemm_qkv<<<dim3(24, 32), 512, 0, stream>>>(xb, wqkvb, q, k, vt);
  flash_attn<<<dim3(64, 8), 256, 0, stream>>>(q, k, vt, attb);
  gemm_out<<<dim3(8, 64), 256, 0, stream>>>(attb, woutb, b_out, out);
}

// Round 7
// 242.809 us; speedup vs baseline: 1.0825x; 1.0220x over previous
//
#include <hip/hip_runtime.h>
#include <stdint.h>

// MultiHeadAttention: B=4, T=2048, C=1024, H=16, D=64, causal, scale=1/8.
// R15: gemm_out -> R13's 8-phase counted-vmcnt schedule (BM=256 BN=128
// BK=64, 512 thr, 96KB LDS dbuf, vmcnt(0) only at tile boundary, swizzle
// (c&7)^(row&7) both-sides). Grid (8,32) = 256 blocks = exactly 1/CU.
// Epilogue: direct fp32 stores + bias. flash_attn (R14 4-q-tile), gemm_qkv
// (R13 8-phase), cast_all unchanged.
//
// MFMA 16x16x32 bf16 layouts:
//   A frag: m = lane&15, k = (lane>>4)*8 + j
//   B frag: n = lane&15, k = (lane>>4)*8 + j
//   C/D:    col = lane&15, row = (lane>>4)*4 + reg

typedef __attribute__((ext_vector_type(8))) short bf16x8;
typedef __attribute__((ext_vector_type(4))) float f32x4;

#define EXP2F(x) __builtin_amdgcn_exp2f(x)
#define SL2E 0.18033688011112042f  /* 0.125 * log2(e) */
#define FIXED_M 15.0f

template <bool B> struct BoolC { static constexpr bool value = B; };
template <int I> struct IntC { static constexpr int value = I; };

__device__ __forceinline__ short f2bf(float f) {
  union { float f; unsigned u; } c; c.f = f;
  unsigned u = c.u;
  unsigned r = (u + 0x7fffu + ((u >> 16) & 1u)) >> 16;
  return (short)(unsigned short)r;
}

// sc[j][r] = S at LDS K position 16j + 4kq + r, q = mrow (log2 units).
// Direct in-lane pack -> PV A-fragments (rho relabeling, see flash_attn).
__device__ __forceinline__ void softmax_pack(const f32x4* sc, bf16x8& pa0, bf16x8& pa1) {
  union U { int i[4]; bf16x8 v; };
  U u0, u1;
#pragma unroll
  for (int j = 0; j < 4; ++j) {
    float p0 = EXP2F(sc[j][0]);
    float p1 = EXP2F(sc[j][1]);
    float p2 = EXP2F(sc[j][2]);
    float p3 = EXP2F(sc[j][3]);
    int w0, w1;
    asm("v_cvt_pk_bf16_f32 %0, %1, %2" : "=v"(w0) : "v"(p0), "v"(p1));
    asm("v_cvt_pk_bf16_f32 %0, %1, %2" : "=v"(w1) : "v"(p2), "v"(p3));
    if (j < 2) { u0.i[j * 2] = w0; u0.i[j * 2 + 1] = w1; }
    else       { u1.i[(j - 2) * 2] = w0; u1.i[(j - 2) * 2 + 1] = w1; }
  }
  pa0 = u0.v;
  pa1 = u1.v;
}

// async 16B global -> LDS (dest = wave-uniform base + lane*16)
__device__ __forceinline__ void llds16(const short* g, short* l) {
  __builtin_amdgcn_global_load_lds(
      (const __attribute__((address_space(1))) unsigned int*)g,
      (__attribute__((address_space(3))) unsigned int*)l, 16, 0, 0);
}

// One launch for all three f32->bf16 casts. Ranges are exact multiples of
// 256 blocks: x = 8192, w_qkv = 3072, w_out = 1024.
__global__ __launch_bounds__(256) void cast_all(
    const float* __restrict__ x, const float* __restrict__ wq,
    const float* __restrict__ wo, short* __restrict__ xb,
    short* __restrict__ wqb, short* __restrict__ wob) {
  const int b = blockIdx.x;
  const float* src;
  short* dst;
  int idx;
  if (b < 8192)        { src = x;  dst = xb;  idx = b * 256 + threadIdx.x; }
  else if (b < 11264)  { src = wq; dst = wqb; idx = (b - 8192) * 256 + threadIdx.x; }
  else                 { src = wo; dst = wob; idx = (b - 11264) * 256 + threadIdx.x; }
  float4 f = ((const float4*)src)[idx];
  short4 o;
  o.x = f2bf(f.x); o.y = f2bf(f.y); o.z = f2bf(f.z); o.w = f2bf(f.w);
  ((short4*)dst)[idx] = o;
}

// ---------------------------------------------------------------------------
// QKV GEMM (B^T): 8-phase counted-vmcnt schedule (R13). BM=256 BN=128 BK=64,
// 512 thr (8 waves, 4Mx2N), LDS 96KB double-buffered. vmcnt(0) only at tile
// boundary; staging swizzle (c&7)^(row&7) on global source + same XOR on
// reads. Epilogue corner-turn.
// ---------------------------------------------------------------------------
__global__ __launch_bounds__(512) void gemm_qkv(
    const short* __restrict__ A, const short* __restrict__ Bw,
    short* __restrict__ Qo, short* __restrict__ Ko, short* __restrict__ Vt) {
  const int K = 1024;
  __shared__ short smem[49152];  // 96 KB
  const int tid = threadIdx.x;
  const int lane = tid & 63;
  const int wave = tid >> 6;     // 0..7
  const int wr = wave >> 1;      // 0..3 (M quarter, 64 rows)
  const int wc = wave & 1;       // 0..1 (N half, 64 cols)
  const int m0 = blockIdx.y * 256;
  const int n0 = blockIdx.x * 128;
  const int mrow = lane & 15;
  const int kq = lane >> 4;

  f32x4 acc[4][4];
#pragma unroll
  for (int i = 0; i < 4; ++i)
#pragma unroll
    for (int j = 0; j < 4; ++j) acc[i][j] = (f32x4){0.f, 0.f, 0.f, 0.f};

  auto stageA = [&](int t, int buf, int ca) {
    const int c = ca * 512 + tid;
    const int row = c >> 3;                    // 0..255
    const int sc = (c & 7) ^ (row & 7);
    llds16(A + (size_t)(m0 + row) * K + t * 64 + sc * 8,
           &smem[buf * 24576 + c * 8]);
  };
  auto stageB = [&](int t, int buf, int cb) {
    const int c = cb * 512 + tid;
    const int row = c >> 3;                    // 0..127
    const int sc = (c & 7) ^ (row & 7);
    llds16(Bw + (size_t)(n0 + row) * K + t * 64 + sc * 8,
           &smem[buf * 24576 + 16384 + c * 8]);
  };

  auto rdA = [&](const short* lA, int i, int kk) -> bf16x8 {
    const int row = wr * 64 + i * 16 + mrow;
    const int ch = (kq + 4 * kk) ^ (row & 7);
    return *(const bf16x8*)&lA[row * 64 + ch * 8];
  };
  auto rdB = [&](const short* lB, int j, int kk) -> bf16x8 {
    const int row = wc * 64 + j * 16 + mrow;
    const int ch = (kq + 4 * kk) ^ (row & 7);
    return *(const bf16x8*)&lB[row * 64 + ch * 8];
  };

  stageA(0, 0, 0); stageA(0, 0, 1); stageA(0, 0, 2); stageA(0, 0, 3);
  stageB(0, 0, 0); stageB(0, 0, 1);
  asm volatile("s_waitcnt vmcnt(0)" ::: "memory");
  __syncthreads();

#define PHASE_TAIL()                                         \
  __builtin_amdgcn_s_barrier();                              \
  asm volatile("s_waitcnt lgkmcnt(0)" ::: "memory");         \
  __builtin_amdgcn_sched_barrier(0);                         \
  __builtin_amdgcn_s_setprio(1);

#define PHASE_END()                                          \
  __builtin_amdgcn_s_setprio(0);                             \
  __builtin_amdgcn_sched_barrier(0);                         \
  __builtin_amdgcn_s_barrier();

  for (int t = 0; t < 16; ++t) {
    const int buf = t & 1;
    const int nb = buf ^ 1;
    const short* lA = &smem[buf * 24576];
    const short* lB = lA + 16384;
    bf16x8 a0, a1, a2, a3, bf0, bf1, bf2, bf3;

    a0 = rdA(lA, 0, 0); a1 = rdA(lA, 1, 0);
    bf0 = rdB(lB, 0, 0); bf1 = rdB(lB, 1, 0);
    bf2 = rdB(lB, 2, 0); bf3 = rdB(lB, 3, 0);
    if (t < 15) { stageA(t + 1, nb, 0); stageA(t + 1, nb, 1); }
    PHASE_TAIL();
    acc[0][0] = __builtin_amdgcn_mfma_f32_16x16x32_bf16(a0, bf0, acc[0][0], 0, 0, 0);
    acc[0][1] = __builtin_amdgcn_mfma_f32_16x16x32_bf16(a0, bf1, acc[0][1], 0, 0, 0);
    acc[0][2] = __builtin_amdgcn_mfma_f32_16x16x32_bf16(a0, bf2, acc[0][2], 0, 0, 0);
    acc[0][3] = __builtin_amdgcn_mfma_f32_16x16x32_bf16(a0, bf3, acc[0][3], 0, 0, 0);
    acc[1][0] = __builtin_amdgcn_mfma_f32_16x16x32_bf16(a1, bf0, acc[1][0], 0, 0, 0);
    acc[1][1] = __builtin_amdgcn_mfma_f32_16x16x32_bf16(a1, bf1, acc[1][1], 0, 0, 0);
    acc[1][2] = __builtin_amdgcn_mfma_f32_16x16x32_bf16(a1, bf2, acc[1][2], 0, 0, 0);
    acc[1][3] = __builtin_amdgcn_mfma_f32_16x16x32_bf16(a1, bf3, acc[1][3], 0, 0, 0);
    PHASE_END();

    a2 = rdA(lA, 2, 0); a3 = rdA(lA, 3, 0);
    if (t < 15) { stageA(t + 1, nb, 2); stageA(t + 1, nb, 3); }
    PHASE_TAIL();
    acc[2][0] = __builtin_amdgcn_mfma_f32_16x16x32_bf16(a2, bf0, acc[2][0], 0, 0, 0);
    acc[2][1] = __builtin_amdgcn_mfma_f32_16x16x32_bf16(a2, bf1, acc[2][1], 0, 0, 0);
    acc[2][2] = __builtin_amdgcn_mfma_f32_16x16x32_bf16(a2, bf2, acc[2][2], 0, 0, 0);
    acc[2][3] = __builtin_amdgcn_mfma_f32_16x16x32_bf16(a2, bf3, acc[2][3], 0, 0, 0);
    acc[3][0] = __builtin_amdgcn_mfma_f32_16x16x32_bf16(a3, bf0, acc[3][0], 0, 0, 0);
    acc[3][1] = __builtin_amdgcn_mfma_f32_16x16x32_bf16(a3, bf1, acc[3][1], 0, 0, 0);
    acc[3][2] = __builtin_amdgcn_mfma_f32_16x16x32_bf16(a3, bf2, acc[3][2], 0, 0, 0);
    acc[3][3] = __builtin_amdgcn_mfma_f32_16x16x32_bf16(a3, bf3, acc[3][3], 0, 0, 0);
    PHASE_END();

    a0 = rdA(lA, 0, 1); a1 = rdA(lA, 1, 1);
    bf0 = rdB(lB, 0, 1); bf1 = rdB(lB, 1, 1);
    bf2 = rdB(lB, 2, 1); bf3 = rdB(lB, 3, 1);
    if (t < 15) { stageB(t + 1, nb, 0); stageB(t + 1, nb, 1); }
    PHASE_TAIL();
    acc[0][0] = __builtin_amdgcn_mfma_f32_16x16x32_bf16(a0, bf0, acc[0][0], 0, 0, 0);
    acc[0][1] = __builtin_amdgcn_mfma_f32_16x16x32_bf16(a0, bf1, acc[0][1], 0, 0, 0);
    acc[0][2] = __builtin_amdgcn_mfma_f32_16x16x32_bf16(a0, bf2, acc[0][2], 0, 0, 0);
    acc[0][3] = __builtin_amdgcn_mfma_f32_16x16x32_bf16(a0, bf3, acc[0][3], 0, 0, 0);
    acc[1][0] = __builtin_amdgcn_mfma_f32_16x16x32_bf16(a1, bf0, acc[1][0], 0, 0, 0);
    acc[1][1] = __builtin_amdgcn_mfma_f32_16x16x32_bf16(a1, bf1, acc[1][1], 0, 0, 0);
    acc[1][2] = __builtin_amdgcn_mfma_f32_16x16x32_bf16(a1, bf2, acc[1][2], 0, 0, 0);
    acc[1][3] = __builtin_amdgcn_mfma_f32_16x16x32_bf16(a1, bf3, acc[1][3], 0, 0, 0);
    PHASE_END();

    a2 = rdA(lA, 2, 1); a3 = rdA(lA, 3, 1);
    PHASE_TAIL();
    acc[2][0] = __builtin_amdgcn_mfma_f32_16x16x32_bf16(a2, bf0, acc[2][0], 0, 0, 0);
    acc[2][1] = __builtin_amdgcn_mfma_f32_16x16x32_bf16(a2, bf1, acc[2][1], 0, 0, 0);
    acc[2][2] = __builtin_amdgcn_mfma_f32_16x16x32_bf16(a2, bf2, acc[2][2], 0, 0, 0);
    acc[2][3] = __builtin_amdgcn_mfma_f32_16x16x32_bf16(a2, bf3, acc[2][3], 0, 0, 0);
    acc[3][0] = __builtin_amdgcn_mfma_f32_16x16x32_bf16(a3, bf0, acc[3][0], 0, 0, 0);
    acc[3][1] = __builtin_amdgcn_mfma_f32_16x16x32_bf16(a3, bf1, acc[3][1], 0, 0, 0);
    acc[3][2] = __builtin_amdgcn_mfma_f32_16x16x32_bf16(a3, bf2, acc[3][2], 0, 0, 0);
    acc[3][3] = __builtin_amdgcn_mfma_f32_16x16x32_bf16(a3, bf3, acc[3][3], 0, 0, 0);
    __builtin_amdgcn_s_setprio(0);
    __builtin_amdgcn_sched_barrier(0);
    if (t < 15) asm volatile("s_waitcnt vmcnt(0)" ::: "memory");
    __builtin_amdgcn_s_barrier();
  }
#undef PHASE_TAIL
#undef PHASE_END

  __syncthreads();   // LDS reuse for epilogue

  const int b = m0 >> 11;            // whole tile lies in one batch
  if (n0 < 2048) {
    const float sc_ = ((n0 >> 10) == 1) ? SL2E : 1.0f;
    short* lC = smem;
#pragma unroll
    for (int i = 0; i < 4; ++i) {
      const int rl = wr * 64 + i * 16 + kq * 4;
#pragma unroll
      for (int j = 0; j < 4; ++j) {
        const int col = wc * 64 + j * 16 + mrow;
#pragma unroll
        for (int r = 0; r < 4; ++r)
          lC[(rl + r) * 132 + col] = f2bf(acc[i][j][r] * sc_);
      }
    }
    __syncthreads();
    short* dst = (n0 >> 10) == 0 ? Qo : Ko;
#pragma unroll
    for (int call = 0; call < 8; ++call) {
      const int cc = call * 512 + tid;
      const int row = cc >> 4;            // 0..255
      const int ch = cc & 15;
      const int t = (m0 & 2047) + row;
      const int c = (n0 + ch * 8) & 1023;
      const int h = c >> 6;
      const int d = c & 63;
      bf16x8 val = *(const bf16x8*)&lC[row * 132 + ch * 8];
      *(bf16x8*)(dst + ((size_t)(b * 16 + h) * 2048 + t) * 64 + d) = val;
    }
  } else {
    short* lCt = smem;
#pragma unroll
    for (int i = 0; i < 4; ++i) {
      const int rl = wr * 64 + i * 16 + kq * 4;
#pragma unroll
      for (int j = 0; j < 4; ++j) {
        const int col = wc * 64 + j * 16 + mrow;
#pragma unroll
        for (int r = 0; r < 4; ++r)
          lCt[col * 264 + rl + r] = f2bf(acc[i][j][r]);
      }
    }
    __syncthreads();
#pragma unroll
    for (int call = 0; call < 8; ++call) {
      const int cc = call * 512 + tid;
      const int col = cc >> 5;            // 0..127
      const int tg = cc & 31;
      const int o = n0 + col;             // 2048..3071
      const int d = o & 63;
      const int h = (o >> 6) & 15;
      const int t = (m0 & 2047) + tg * 8;
      bf16x8 val = *(const bf16x8*)&lCt[col * 264 + tg * 8];
      *(bf16x8*)(Vt + ((size_t)(b * 16 + h) * 64 + d) * 2048 + t) = val;
    }
  }
}

// ---------------------------------------------------------------------------
// Out-proj GEMM R15: 8-phase counted-vmcnt schedule (same as gemm_qkv).
// BM=256 BN=128 BK=64, 512 thr (8 waves, 4Mx2N), 96KB LDS dbuf. Grid
// (8,32) = 256 blocks = exactly 1/CU. Epilogue: direct fp32 stores + bias.
// ---------------------------------------------------------------------------
__global__ __launch_bounds__(512) void gemm_out(
    const short* __restrict__ A, const short* __restrict__ Bw,
    const float* __restrict__ bias, float* __restrict__ Out) {
  const int K = 1024;
  __shared__ short smem[49152];  // 96 KB
  const int tid = threadIdx.x;
  const int lane = tid & 63;
  const int wave = tid >> 6;     // 0..7
  const int wr = wave >> 1;      // 0..3 (M quarter, 64 rows)
  const int wc = wave & 1;       // 0..1 (N half, 64 cols)
  const int m0 = blockIdx.y * 256;
  const int n0 = blockIdx.x * 128;
  const int mrow = lane & 15;
  const int kq = lane >> 4;

  f32x4 acc[4][4];
#pragma unroll
  for (int i = 0; i < 4; ++i)
#pragma unroll
    for (int j = 0; j < 4; ++j) acc[i][j] = (f32x4){0.f, 0.f, 0.f, 0.f};

  auto stageA = [&](int t, int buf, int ca) {
    const int c = ca * 512 + tid;
    const int row = c >> 3;                    // 0..255
    const int sc = (c & 7) ^ (row & 7);
    llds16(A + (size_t)(m0 + row) * K + t * 64 + sc * 8,
           &smem[buf * 24576 + c * 8]);
  };
  auto stageB = [&](int t, int buf, int cb) {
    const int c = cb * 512 + tid;
    const int row = c >> 3;                    // 0..127
    const int sc = (c & 7) ^ (row & 7);
    llds16(Bw + (size_t)(n0 + row) * K + t * 64 + sc * 8,
           &smem[buf * 24576 + 16384 + c * 8]);
  };

  auto rdA = [&](const short* lA, int i, int kk) -> bf16x8 {
    const int row = wr * 64 + i * 16 + mrow;
    const int ch = (kq + 4 * kk) ^ (row & 7);
    return *(const bf16x8*)&lA[row * 64 + ch * 8];
  };
  auto rdB = [&](const short* lB, int j, int kk) -> bf16x8 {
    const int row = wc * 64 + j * 16 + mrow;
    const int ch = (kq + 4 * kk) ^ (row & 7);
    return *(const bf16x8*)&lB[row * 64 + ch * 8];
  };

  stageA(0, 0, 0); stageA(0, 0, 1); stageA(0, 0, 2); stageA(0, 0, 3);
  stageB(0, 0, 0); stageB(0, 0, 1);
  asm volatile("s_waitcnt vmcnt(0)" ::: "memory");
  __syncthreads();

#define PHASE_TAIL()                                         \
  __builtin_amdgcn_s_barrier();                              \
  asm volatile("s_waitcnt lgkmcnt(0)" ::: "memory");         \
  __builtin_amdgcn_sched_barrier(0);                         \
  __builtin_amdgcn_s_setprio(1);

#define PHASE_END()                                          \
  __builtin_amdgcn_s_setprio(0);                             \
  __builtin_amdgcn_sched_barrier(0);                         \
  __builtin_amdgcn_s_barrier();

  for (int t = 0; t < 16; ++t) {
    const int buf = t & 1;
    const int nb = buf ^ 1;
    const short* lA = &smem[buf * 24576];
    const short* lB = lA + 16384;
    bf16x8 a0, a1, a2, a3, bf0, bf1, bf2, bf3;

    a0 = rdA(lA, 0, 0); a1 = rdA(lA, 1, 0);
    bf0 = rdB(lB, 0, 0); bf1 = rdB(lB, 1, 0);
    bf2 = rdB(lB, 2, 0); bf3 = rdB(lB, 3, 0);
    if (t < 15) { stageA(t + 1, nb, 0); stageA(t + 1, nb, 1); }
    PHASE_TAIL();
    acc[0][0] = __builtin_amdgcn_mfma_f32_16x16x32_bf16(a0, bf0, acc[0][0], 0, 0, 0);
    acc[0][1] = __builtin_amdgcn_mfma_f32_16x16x32_bf16(a0, bf1, acc[0][1], 0, 0, 0);
    acc[0][2] = __builtin_amdgcn_mfma_f32_16x16x32_bf16(a0, bf2, acc[0][2], 0, 0, 0);
    acc[0][3] = __builtin_amdgcn_mfma_f32_16x16x32_bf16(a0, bf3, acc[0][3], 0, 0, 0);
    acc[1][0] = __builtin_amdgcn_mfma_f32_16x16x32_bf16(a1, bf0, acc[1][0], 0, 0, 0);
    acc[1][1] = __builtin_amdgcn_mfma_f32_16x16x32_bf16(a1, bf1, acc[1][1], 0, 0, 0);
    acc[1][2] = __builtin_amdgcn_mfma_f32_16x16x32_bf16(a1, bf2, acc[1][2], 0, 0, 0);
    acc[1][3] = __builtin_amdgcn_mfma_f32_16x16x32_bf16(a1, bf3, acc[1][3], 0, 0, 0);
    PHASE_END();

    a2 = rdA(lA, 2, 0); a3 = rdA(lA, 3, 0);
    if (t < 15) { stageA(t + 1, nb, 2); stageA(t + 1, nb, 3); }
    PHASE_TAIL();
    acc[2][0] = __builtin_amdgcn_mfma_f32_16x16x32_bf16(a2, bf0, acc[2][0], 0, 0, 0);
    acc[2][1] = __builtin_amdgcn_mfma_f32_16x16x32_bf16(a2, bf1, acc[2][1], 0, 0, 0);
    acc[2][2] = __builtin_amdgcn_mfma_f32_16x16x32_bf16(a2, bf2, acc[2][2], 0, 0, 0);
    acc[2][3] = __builtin_amdgcn_mfma_f32_16x16x32_bf16(a2, bf3, acc[2][3], 0, 0, 0);
    acc[3][0] = __builtin_amdgcn_mfma_f32_16x16x32_bf16(a3, bf0, acc[3][0], 0, 0, 0);
    acc[3][1] = __builtin_amdgcn_mfma_f32_16x16x32_bf16(a3, bf1, acc[3][1], 0, 0, 0);
    acc[3][2] = __builtin_amdgcn_mfma_f32_16x16x32_bf16(a3, bf2, acc[3][2], 0, 0, 0);
    acc[3][3] = __builtin_amdgcn_mfma_f32_16x16x32_bf16(a3, bf3, acc[3][3], 0, 0, 0);
    PHASE_END();

    a0 = rdA(lA, 0, 1); a1 = rdA(lA, 1, 1);
    bf0 = rdB(lB, 0, 1); bf1 = rdB(lB, 1, 1);
    bf2 = rdB(lB, 2, 1); bf3 = rdB(lB, 3, 1);
    if (t < 15) { stageB(t + 1, nb, 0); stageB(t + 1, nb, 1); }
    PHASE_TAIL();
    acc[0][0] = __builtin_amdgcn_mfma_f32_16x16x32_bf16(a0, bf0, acc[0][0], 0, 0, 0);
    acc[0][1] = __builtin_amdgcn_mfma_f32_16x16x32_bf16(a0, bf1, acc[0][1], 0, 0, 0);
    acc[0][2] = __builtin_amdgcn_mfma_f32_16x16x32_bf16(a0, bf2, acc[0][2], 0, 0, 0);
    acc[0][3] = __builtin_amdgcn_mfma_f32_16x16x32_bf16(a0, bf3, acc[0][3], 0, 0, 0);
    acc[1][0] = __builtin_amdgcn_mfma_f32_16x16x32_bf16(a1, bf0, acc[1][0], 0, 0, 0);
    acc[1][1] = __builtin_amdgcn_mfma_f32_16x16x32_bf16(a1, bf1, acc[1][1], 0, 0, 0);
    acc[1][2] = __builtin_amdgcn_mfma_f32_16x16x32_bf16(a1, bf2, acc[1][2], 0, 0, 0);
    acc[1][3] = __builtin_amdgcn_mfma_f32_16x16x32_bf16(a1, bf3, acc[1][3], 0, 0, 0);
    PHASE_END();

    a2 = rdA(lA, 2, 1); a3 = rdA(lA, 3, 1);
    PHASE_TAIL();
    acc[2][0] = __builtin_amdgcn_mfma_f32_16x16x32_bf16(a2, bf0, acc[2][0], 0, 0, 0);
    acc[2][1] = __builtin_amdgcn_mfma_f32_16x16x32_bf16(a2, bf1, acc[2][1], 0, 0, 0);
    acc[2][2] = __builtin_amdgcn_mfma_f32_16x16x32_bf16(a2, bf2, acc[2][2], 0, 0, 0);
    acc[2][3] = __builtin_amdgcn_mfma_f32_16x16x32_bf16(a2, bf3, acc[2][3], 0, 0, 0);
    acc[3][0] = __builtin_amdgcn_mfma_f32_16x16x32_bf16(a3, bf0, acc[3][0], 0, 0, 0);
    acc[3][1] = __builtin_amdgcn_mfma_f32_16x16x32_bf16(a3, bf1, acc[3][1], 0, 0, 0);
    acc[3][2] = __builtin_amdgcn_mfma_f32_16x16x32_bf16(a3, bf2, acc[3][2], 0, 0, 0);
    acc[3][3] = __builtin_amdgcn_mfma_f32_16x16x32_bf16(a3, bf3, acc[3][3], 0, 0, 0);
    __builtin_amdgcn_s_setprio(0);
    __builtin_amdgcn_sched_barrier(0);
    if (t < 15) asm volatile("s_waitcnt vmcnt(0)" ::: "memory");
    __builtin_amdgcn_s_barrier();
  }
#undef PHASE_TAIL
#undef PHASE_END

  // epilogue: direct fp32 stores + bias
#pragma unroll
  for (int i = 0; i < 4; ++i) {
    const int m = m0 + wr * 64 + i * 16 + kq * 4;
#pragma unroll
    for (int j = 0; j < 4; ++j) {
      const int n = n0 + wc * 64 + j * 16 + mrow;
      const float bb = bias[n];
#pragma unroll
      for (int r = 0; r < 4; ++r)
        Out[(size_t)(m + r) * 1024 + n] = acc[i][j][r] + bb;
    }
  }
}

// ---------------------------------------------------------------------------
// Flash attention R14 (unchanged). Grid (64 bh, 8). Block = 4 waves, FOUR
// q-tiles {bx, 31-bx, 15-bx, 16+bx} (constant 66 seg-tiles/block), one K/Vt
// stream kt = 0..31-bx. Tiles processed in pairs sharing K/V fragment
// reads. Swapped QK^T (mfma(K,Q)) with rho-permuted K rows -> softmax fully
// in-register, NO cross-lane ops. Fixed-max softmax (M=15 via MFMA C-init);
// l via ones-MFMA. Double-buffered staging with counted vmcnt(4) + dual raw
// s_barrier. LDS = 32 KB.
// ---------------------------------------------------------------------------
__global__ __launch_bounds__(256) void flash_attn(
    const short* __restrict__ Qg, const short* __restrict__ Kg,
    const short* __restrict__ Vtg, short* __restrict__ Og) {
  const int T = 2048;
  __shared__ short lK[2][64 * 64];
  __shared__ short lVt[2][64 * 64];
  const int tid = threadIdx.x;
  const int lane = tid & 63;
  const int wave = tid >> 6;
  const int bh = blockIdx.x;
  const int bx = blockIdx.y;         // 0..7
  const int mrow = lane & 15;
  const int kq = lane >> 4;
  const int swz = mrow & 7;
  const size_t base = (size_t)bh * T * 64;   // Q,K: [bh][t][d]
  const size_t vbase = (size_t)bh * 64 * T;  // Vt:  [bh][d][t]

  int qts[4];
  qts[0] = bx;         // pair 0: active kt <= bx
  qts[1] = 31 - bx;    // pair 0 anchor: active all kt (ktmax)
  qts[2] = 15 - bx;    // pair 1: active kt <= 15-bx
  qts[3] = 16 + bx;    // pair 1 anchor: active kt <= 16+bx

  const bf16x8 ones = {0x3F80, 0x3F80, 0x3F80, 0x3F80, 0x3F80, 0x3F80, 0x3F80, 0x3F80};

  bf16x8 aq0[4], aq1[4];
#pragma unroll
  for (int s = 0; s < 4; ++s) {
    const short* qp = Qg + base + (size_t)(qts[s] * 64 + wave * 16 + mrow) * 64 + kq * 8;
    aq0[s] = *(const bf16x8*)qp;
    aq1[s] = *(const bf16x8*)(qp + 32);
  }

  f32x4 acc[4][4], lac[4];
#pragma unroll
  for (int s = 0; s < 4; ++s) {
    lac[s] = (f32x4){0.f, 0.f, 0.f, 0.f};
#pragma unroll
    for (int jd = 0; jd < 4; ++jd) acc[s][jd] = (f32x4){0.f, 0.f, 0.f, 0.f};
  }

  auto stage = [&](int nt, int buf) {
#pragma unroll
    for (int call = 0; call < 2; ++call) {
      const int cb = call * 256 + wave * 64;
      const int c = cb + lane;
      const int row = c >> 3;
      const int scol = (c & 7) ^ (row & 7);
      // K row permutation rho: LDS row p holds key with bit-permuted index
      // (b5,b4,b3,b2 -> b5,b3,b2,b4) so the in-lane P pack IS the PV A-frag.
      const int grow = (row & 0x23) | ((row & 0x0C) << 1) | ((row & 0x10) >> 2);
      llds16(Kg + base + (size_t)(nt * 64 + grow) * 64 + scol * 8, &lK[buf][cb * 8]);
      llds16(Vtg + vbase + (size_t)row * T + nt * 64 + scol * 8, &lVt[buf][cb * 8]);
    }
  };

  // seg for tile pair (PI, PI+1): anchor tile PI+1 assumed active; tile PI
  // active iff ACT0. K/V fragments read once, shared by both tiles.
  auto seg = [&](auto Aa, auto Pi, const short* K_, const short* Vt_, int kt) {
    constexpr bool ACT0 = decltype(Aa)::value;
    constexpr int pi = decltype(Pi)::value;
    f32x4 sc0[4], sc1[4];
#pragma unroll
    for (int j = 0; j < 4; ++j) {
      const short* krow = &K_[(j * 16 + mrow) * 64];
      bf16x8 kb0 = *(const bf16x8*)&krow[(kq ^ swz) * 8];
      bf16x8 kb1 = *(const bf16x8*)&krow[((4 + kq) ^ swz) * 8];
      __builtin_amdgcn_s_setprio(1);
      f32x4 ss = (f32x4){-FIXED_M, -FIXED_M, -FIXED_M, -FIXED_M};
      ss = __builtin_amdgcn_mfma_f32_16x16x32_bf16(kb0, aq0[pi + 1], ss, 0, 0, 0);
      ss = __builtin_amdgcn_mfma_f32_16x16x32_bf16(kb1, aq1[pi + 1], ss, 0, 0, 0);
      sc1[j] = ss;
      if constexpr (ACT0) {
        f32x4 s2 = (f32x4){-FIXED_M, -FIXED_M, -FIXED_M, -FIXED_M};
        s2 = __builtin_amdgcn_mfma_f32_16x16x32_bf16(kb0, aq0[pi], s2, 0, 0, 0);
        s2 = __builtin_amdgcn_mfma_f32_16x16x32_bf16(kb1, aq1[pi], s2, 0, 0, 0);
        sc0[j] = s2;
      }
      __builtin_amdgcn_s_setprio(0);
    }

    // causal masks (diagonal tiles). sc[j][r] is key
    // kt*64 + 32*(j>>1) + 8*kq + 4*(j&1) + r under rho.
    if (kt == qts[pi + 1]) {
      const int qcol = qts[pi + 1] * 64 + wave * 16 + mrow;
#pragma unroll
      for (int j = 0; j < 4; ++j) {
        const int keyb = kt * 64 + ((j & 2) << 4) + (kq << 3) + ((j & 1) << 2);
#pragma unroll
        for (int r = 0; r < 4; ++r)
          if (keyb + r > qcol) sc1[j][r] = -1e30f;
      }
    }
    if constexpr (ACT0) {
      if (kt == qts[pi]) {
        const int qcol = qts[pi] * 64 + wave * 16 + mrow;
#pragma unroll
        for (int j = 0; j < 4; ++j) {
          const int keyb = kt * 64 + ((j & 2) << 4) + (kq << 3) + ((j & 1) << 2);
#pragma unroll
          for (int r = 0; r < 4; ++r)
            if (keyb + r > qcol) sc0[j][r] = -1e30f;
        }
      }
    }

    bf16x8 pa0_1, pa1_1, pa0_0, pa1_0;
    softmax_pack(sc1, pa0_1, pa1_1);
    lac[pi + 1] = __builtin_amdgcn_mfma_f32_16x16x32_bf16(pa0_1, ones, lac[pi + 1], 0, 0, 0);
    lac[pi + 1] = __builtin_amdgcn_mfma_f32_16x16x32_bf16(pa1_1, ones, lac[pi + 1], 0, 0, 0);
    if constexpr (ACT0) {
      softmax_pack(sc0, pa0_0, pa1_0);
      lac[pi] = __builtin_amdgcn_mfma_f32_16x16x32_bf16(pa0_0, ones, lac[pi], 0, 0, 0);
      lac[pi] = __builtin_amdgcn_mfma_f32_16x16x32_bf16(pa1_0, ones, lac[pi], 0, 0, 0);
    }

#pragma unroll
    for (int jd = 0; jd < 4; ++jd) {
      const short* vrow = &Vt_[(jd * 16 + mrow) * 64];
      bf16x8 vb0 = *(const bf16x8*)&vrow[(kq ^ swz) * 8];
      bf16x8 vb1 = *(const bf16x8*)&vrow[((4 + kq) ^ swz) * 8];
      __builtin_amdgcn_s_setprio(1);
      acc[pi + 1][jd] = __builtin_amdgcn_mfma_f32_16x16x32_bf16(pa0_1, vb0, acc[pi + 1][jd], 0, 0, 0);
      acc[pi + 1][jd] = __builtin_amdgcn_mfma_f32_16x16x32_bf16(pa1_1, vb1, acc[pi + 1][jd], 0, 0, 0);
      if constexpr (ACT0) {
        acc[pi][jd] = __builtin_amdgcn_mfma_f32_16x16x32_bf16(pa0_0, vb0, acc[pi][jd], 0, 0, 0);
        acc[pi][jd] = __builtin_amdgcn_mfma_f32_16x16x32_bf16(pa1_0, vb1, acc[pi][jd], 0, 0, 0);
      }
      __builtin_amdgcn_s_setprio(0);
    }
  };

  stage(0, 0);
  const int ktmax = qts[1];
  for (int kt = 0; kt <= ktmax; ++kt) {
    const int bcur = kt & 1;
    if (kt < ktmax) {
      stage(kt + 1, bcur ^ 1);
      asm volatile("s_waitcnt vmcnt(4)" ::: "memory");  // kt's 4 landed
    } else {
      asm volatile("s_waitcnt vmcnt(0)" ::: "memory");
    }
    __builtin_amdgcn_s_barrier();   // all waves' kt loads landed
    const short* K_ = lK[bcur];
    const short* Vt_ = lVt[bcur];
    // pair 0: anchor qts[1] active for all kt
    if (kt <= qts[0]) seg(BoolC<true>{}, IntC<0>{}, K_, Vt_, kt);
    else              seg(BoolC<false>{}, IntC<0>{}, K_, Vt_, kt);
    // pair 1: anchor qts[3] active while kt <= 16+bx
    if (kt <= qts[3]) {
      if (kt <= qts[2]) seg(BoolC<true>{}, IntC<1 * 2>{}, K_, Vt_, kt);
      else              seg(BoolC<false>{}, IntC<1 * 2>{}, K_, Vt_, kt);
    }
    __builtin_amdgcn_s_barrier();   // buf[bcur] free for restage next iter
  }

  const int b = bh >> 4;
  const int h = bh & 15;
#pragma unroll
  for (int s = 0; s < 4; ++s) {
#pragma unroll
    for (int r = 0; r < 4; ++r) {
      const float inv = 1.0f / lac[s][r];
      const int t = qts[s] * 64 + wave * 16 + kq * 4 + r;
#pragma unroll
      for (int jd = 0; jd < 4; ++jd) {
        const int col = h * 64 + jd * 16 + mrow;
        Og[((size_t)b * 2048 + t) * 1024 + col] = f2bf(acc[s][jd][r] * inv);
      }
    }
  }
}

extern "C" void kernel_launch(void* const* d_in, const int* in_sizes, int n_in,
                              void* d_out, int out_size, void* d_ws, size_t ws_size,
                              hipStream_t stream) {
  const float* x = (const float*)d_in[0];
  const float* w_qkv = (const float*)d_in[1];
  const float* w_out = (const float*)d_in[2];
  const float* b_out = (const float*)d_in[3];
  float* out = (float*)d_out;

  char* ws = (char*)d_ws;
  const size_t NX = 8192ull * 1024;
  const size_t NWQ = 3072ull * 1024;
  const size_t NWO = 1024ull * 1024;
  const size_t NQ = 64ull * 2048 * 64;
  size_t off = 0;
  short* xb    = (short*)(ws + off); off += NX * 2;
  short* wqkvb = (short*)(ws + off); off += NWQ * 2;
  short* woutb = (short*)(ws + off); off += NWO * 2;
  short* q     = (short*)(ws + off); off += NQ * 2;
  short* k     = (short*)(ws + off); off += NQ * 2;
  short* vt    = (short*)(ws + off); off += NQ * 2;  // V stored transposed [bh][d][t]
  short* attb  = (short*)(ws + off); off += NX * 2;
  if (off > ws_size) return;

  cast_all<<<12288, 256, 0, stream>>>(x, w_qkv, w_out, xb, wqkvb, woutb);
  gemm_qkv<<<dim3(24, 32), 512, 0, stream>>>(xb, wqkvb, q, k, vt);
  flash_attn<<<dim3(64, 8), 256, 0, stream>>>(q, k, vt, attb);
  gemm_out<<<dim3(8, 32), 512, 0, stream>>>(attb, woutb, b_out, out);
}